// Round 19
// baseline (236.754 us; speedup 1.0000x reference)
//
#include <hip/hip_runtime.h>
#include <hip/hip_bf16.h>

#define ALPHA 0.2f
#define LOG2E 1.4426950408889634f

using short8  = __attribute__((ext_vector_type(8))) short;
using short4v = __attribute__((ext_vector_type(4))) short;
using f32x4   = __attribute__((ext_vector_type(4))) float;
using int4v   = __attribute__((ext_vector_type(4))) int;

static __device__ __forceinline__ float b2f(short s) {
    union { float f; unsigned u; } v; v.u = ((unsigned)(unsigned short)s) << 16; return v.f;
}
static __device__ __forceinline__ short f2bf(float f) {
    __hip_bfloat16 h = __float2bfloat16(f);
    return *reinterpret_cast<short*>(&h);
}
static __device__ __forceinline__ float fexp2(float x) {
    return __builtin_amdgcn_exp2f(x);          // v_exp_f32: D = 2^S0
}
static __device__ __forceinline__ void gload_lds16(const void* g, void* l) {
    __builtin_amdgcn_global_load_lds(
        (const __attribute__((address_space(1))) unsigned*)g,
        (__attribute__((address_space(3))) unsigned*)l, 16, 0, 0);
}

// ---------------- fused prep: adjbits | cast_x | w1t | w2t ----------------------
__global__ __launch_bounds__(256) void k_prep(
        const int* __restrict__ adj, unsigned* __restrict__ adjb,
        const float* __restrict__ x, short* __restrict__ xb,
        const float* __restrict__ W1, short* __restrict__ W1T,
        const float* __restrict__ W2, short* __restrict__ W2T) {
    int bid = blockIdx.x, t = threadIdx.x;
    if (bid < 32768) {                       // adj int32 -> bit-packed
        int idx = bid * 256 + t;
        int lane = t & 63;
        unsigned long long m = __ballot(adj[idx] > 0);
        if ((lane & 31) == 0) adjb[idx >> 5] = (unsigned)(m >> (lane & 32));
    } else if (bid < 38912) {                // x f32 -> bf16 (x4)
        int idx = (bid - 32768) * 256 + t;
        f32x4 v = ((const f32x4*)x)[idx];
        short4v o;
        o[0] = f2bf(v[0]); o[1] = f2bf(v[1]); o[2] = f2bf(v[2]); o[3] = f2bf(v[3]);
        ((short4v*)xb)[idx] = o;
    } else if (bid < 41984) {                // W1T[n][k] = W1[h][k][o]
        int idx = (bid - 38912) * 256 + t;
        int n = idx / 768, k = idx - n * 768;
        int h = n >> 7, o = n & 127;
        W1T[idx] = f2bf(W1[(h * 768 + k) * 128 + o]);
    } else {                                 // W2T[n][k] = W2[0][k][n]
        int idx = (bid - 41984) * 256 + t;
        int n = idx >> 10, k = idx & 1023;
        W2T[idx] = f2bf(W2[k * 128 + n]);
    }
}

// ---------------- bf16 MFMA GEMM 128x128, BK=64 pair, XCD-swz ------------------
// Layer-1 specialized: fused s1/s2 epilogue; coalesced C-store via LDS bounce.
__global__ __launch_bounds__(256) void k_gemm_bt(
        const short* __restrict__ A, const short* __restrict__ Bt,
        short* __restrict__ Ct, int K, int Ncols,
        const float* __restrict__ a1, const float* __restrict__ a2,
        float* __restrict__ s1, float* __restrict__ s2) {
    int tid = threadIdx.x, wave = tid >> 6, lane = tid & 63;
    int lr = lane & 15, lg = lane >> 4;
    int flat = blockIdx.y * gridDim.x + blockIdx.x;
    int chunkw = (gridDim.x * gridDim.y) >> 3;
    int swz = (flat & 7) * chunkw + (flat >> 3);
    int bx = swz % gridDim.x, by = swz / gridDim.x;
    int m0 = bx * 128, n0 = by * 128;
    int wm = (wave >> 1) * 64, wn = (wave & 1) * 64;
    __shared__ short lsA[2][128 * 64], lsB[2][128 * 64];
    __shared__ float sred1[2][128], sred2[2][128];
    f32x4 acc[4][4];
#pragma unroll
    for (int i = 0; i < 4; i++)
#pragma unroll
        for (int j = 0; j < 4; j++) acc[i][j] = (f32x4){0.f, 0.f, 0.f, 0.f};

    auto stage = [&](int bufsel, int k0) {
#pragma unroll
        for (int s = 0; s < 4; s++) {
            int chunk = s * 256 + tid;          // 1024 chunks of 16B per matrix
            int r = chunk >> 3, c = chunk & 7;
            int csrc = c ^ (r & 7);             // inverse-swizzled source
            gload_lds16(A + (size_t)(m0 + r) * K + k0 + csrc * 8, &lsA[bufsel][chunk * 8]);
            gload_lds16(Bt + (size_t)(n0 + r) * K + k0 + csrc * 8, &lsB[bufsel][chunk * 8]);
        }
    };
    auto compute = [&](const short* la, const short* lb) {
#pragma unroll
        for (int kk = 0; kk < 2; kk++) {
            short8 a[4], bb[4];
#pragma unroll
            for (int f = 0; f < 4; f++) {
                int ra = wm + f * 16 + lr, rb = wn + f * 16 + lr;
                a[f]  = *(const short8*)(la + ra * 64 + (((kk * 4 + lg) ^ (ra & 7)) * 8));
                bb[f] = *(const short8*)(lb + rb * 64 + (((kk * 4 + lg) ^ (rb & 7)) * 8));
            }
#pragma unroll
            for (int fm = 0; fm < 4; fm++)
#pragma unroll
                for (int fn = 0; fn < 4; fn++)
                    acc[fm][fn] = __builtin_amdgcn_mfma_f32_16x16x32_bf16(a[fm], bb[fn], acc[fm][fn], 0, 0, 0);
        }
    };
    stage(0, 0);
    __syncthreads();
    for (int k2 = 0; k2 < K; k2 += 128) {       // requires K % 128 == 0
        stage(1, k2 + 64);
        compute(lsA[0], lsB[0]);
        __syncthreads();
        if (k2 + 128 < K) stage(0, k2 + 128);
        compute(lsA[1], lsB[1]);
        __syncthreads();
    }
    // C-store via LDS bounce: stg[n_local][i4 swizzled] -> 256B-contiguous writes
    short* stg = &lsA[0][0];                    // 32KB, free after K-loop
#pragma unroll
    for (int fm = 0; fm < 4; fm++) {
#pragma unroll
        for (int fn = 0; fn < 4; fn++) {
            int nl = wn + fn * 16 + lr;
            int i4w = (wm + fm * 16 + lg * 4) >> 2;
            short4v st;
            st[0] = f2bf(acc[fm][fn][0]); st[1] = f2bf(acc[fm][fn][1]);
            st[2] = f2bf(acc[fm][fn][2]); st[3] = f2bf(acc[fm][fn][3]);
            *(short4v*)(stg + (nl * 32 + (i4w ^ (nl & 31))) * 4) = st;
        }
    }
    __syncthreads();
    size_t gbase = ((size_t)(m0 >> 10) * Ncols + n0) * 1024 + (m0 & 1023);
#pragma unroll
    for (int it = 0; it < 8; it++) {
        int idx8 = it * 256 + tid;              // 2048 units of 16B
        int nl = idx8 >> 4, p = idx8 & 15;
        int i4a = 2 * p, i4b = 2 * p + 1;
        short4v lo = *(short4v*)(stg + (nl * 32 + (i4a ^ (nl & 31))) * 4);
        short4v hi = *(short4v*)(stg + (nl * 32 + (i4b ^ (nl & 31))) * 4);
        short8 v;
#pragma unroll
        for (int r = 0; r < 4; r++) { v[r] = lo[r]; v[r + 4] = hi[r]; }
        *(short8*)(Ct + gbase + (size_t)nl * 1024 + p * 8) = v;
    }
    // fused s1/s2 epilogue (layer 1 only: a1 != nullptr)
    if (a1 != nullptr) {
        int h = by;                              // n-block == head
        float av1[4], av2[4];
#pragma unroll
        for (int fn = 0; fn < 4; fn++) {
            int o = wn + fn * 16 + lr;
            av1[fn] = a1[h * 128 + o];
            av2[fn] = a2[h * 128 + o];
        }
        int wcol = wave & 1;
#pragma unroll
        for (int fm = 0; fm < 4; fm++)
#pragma unroll
            for (int r = 0; r < 4; r++) {
                float v1 = acc[fm][0][r] * av1[0] + acc[fm][1][r] * av1[1]
                         + acc[fm][2][r] * av1[2] + acc[fm][3][r] * av1[3];
                float v2 = acc[fm][0][r] * av2[0] + acc[fm][1][r] * av2[1]
                         + acc[fm][2][r] * av2[2] + acc[fm][3][r] * av2[3];
#pragma unroll
                for (int off = 1; off < 16; off <<= 1) {
                    v1 += __shfl_xor(v1, off);
                    v2 += __shfl_xor(v2, off);
                }
                if (lr == 0) {
                    int il = wm + fm * 16 + lg * 4 + r;
                    sred1[wcol][il] = v1;
                    sred2[wcol][il] = v2;
                }
            }
        __syncthreads();
        if (tid < 128) {
            int b = m0 >> 10;
            int irow = (b * 8 + h) * 1024 + (m0 & 1023) + tid;
            s1[irow] = (sred1[0][tid] + sred1[1][tid]) * LOG2E;
            s2[irow] = (sred2[0][tid] + sred2[1][tid]) * LOG2E;
        }
    }
}

// ---------------- bf16 MFMA GEMM 64x64 (layer-2) -------------------------------
__global__ __launch_bounds__(256) void k_gemm64(
        const short* __restrict__ A, const short* __restrict__ Bt,
        short* __restrict__ Ct, int K, int Ncols) {
    int tid = threadIdx.x, wave = tid >> 6, lane = tid & 63;
    int lr = lane & 15, lg = lane >> 4;
    int flat = blockIdx.y * gridDim.x + blockIdx.x;
    int chunkw = (gridDim.x * gridDim.y) >> 3;
    int swz = (flat & 7) * chunkw + (flat >> 3);
    int bx = swz % gridDim.x, by = swz / gridDim.x;
    int m0 = bx * 64, n0 = by * 64;
    int wm = (wave >> 1) * 32, wn = (wave & 1) * 32;
    __shared__ short lsA[2][64 * 32], lsB[2][64 * 32];
    f32x4 acc[2][2];
#pragma unroll
    for (int i = 0; i < 2; i++)
#pragma unroll
        for (int j = 0; j < 2; j++) acc[i][j] = (f32x4){0.f, 0.f, 0.f, 0.f};

    auto stage = [&](int bufsel, int k0) {
        int r = tid >> 2, c = tid & 3;
        int csrc = c ^ (r & 3);
        int base = (wave * 64) * 8;
        gload_lds16(A + (size_t)(m0 + r) * K + k0 + csrc * 8, &lsA[bufsel][base]);
        gload_lds16(Bt + (size_t)(n0 + r) * K + k0 + csrc * 8, &lsB[bufsel][base]);
    };
    stage(0, 0);
    __syncthreads();
    int buf = 0;
    for (int k0 = 0; k0 < K; k0 += 32) {
        if (k0 + 32 < K) stage(buf ^ 1, k0 + 32);
        short8 a[2], bb[2];
#pragma unroll
        for (int f = 0; f < 2; f++) {
            int ra = wm + f * 16 + lr, rb = wn + f * 16 + lr;
            a[f]  = *(const short8*)(&lsA[buf][ra * 32 + ((lg ^ (ra & 3)) * 8)]);
            bb[f] = *(const short8*)(&lsB[buf][rb * 32 + ((lg ^ (rb & 3)) * 8)]);
        }
#pragma unroll
        for (int fm = 0; fm < 2; fm++)
#pragma unroll
            for (int fn = 0; fn < 2; fn++)
                acc[fm][fn] = __builtin_amdgcn_mfma_f32_16x16x32_bf16(a[fm], bb[fn], acc[fm][fn], 0, 0, 0);
        __syncthreads();
        buf ^= 1;
    }
#pragma unroll
    for (int fm = 0; fm < 2; fm++) {
        int mb = m0 + wm + fm * 16 + lg * 4;
        size_t obase = ((size_t)(mb >> 10) * Ncols) * 1024 + (mb & 1023);
#pragma unroll
        for (int fn = 0; fn < 2; fn++) {
            int n = n0 + wn + fn * 16 + lr;
            short4v st;
            st[0] = f2bf(acc[fm][fn][0]); st[1] = f2bf(acc[fm][fn][1]);
            st[2] = f2bf(acc[fm][fn][2]); st[3] = f2bf(acc[fm][fn][3]);
            *(short4v*)(Ct + obase + (size_t)n * 1024) = st;
        }
    }
}

// ---------------- GAT layer-1 attention: NO LDS staging — h direct from L2 -----
// Panel (256KB) is L2-resident via XCD swizzle. No barriers in the j-loop:
// waves run independently, VALU p-gen of one wave overlaps VMEM of others.
// LDS = 4KB (s2 only) -> occupancy cap moves to waves (up to 32/CU).
__global__ __launch_bounds__(512) void k_attn1(
        const short* __restrict__ ht, const unsigned* __restrict__ adjb,
        const float* __restrict__ s1, const float* __restrict__ s2,
        short* __restrict__ out) {
    int flat = blockIdx.y * 8 + blockIdx.x;
    int swz = (flat & 7) * 64 + (flat >> 3);    // 512 blocks: bijective
    int bh = swz >> 3, bxi = swz & 7;
    int b = bh >> 3, h = bh & 7;
    int tid = threadIdx.x, wave = tid >> 6, lane = tid & 63;
    int lr = lane & 15, lg = lane >> 4;
    int ic = bxi * 128 + wave * 16 + lr;
    int row = bh * 1024 + ic;
    float s1i = s1[row];                        // pre-scaled by log2e
    const unsigned long long* abrow =
        (const unsigned long long*)(adjb + ((size_t)(b << 10) + ic) * 32);
    const float* s2r = s2 + bh * 1024;
    const short* hbase = ht + (size_t)bh * 131072;
    const short* hlane = hbase + (size_t)lr * 1024 + lg * 8;   // + fm*16*1024 + j0

    __shared__ float ls2[1024];       // staged s2 row (4KB) — only LDS use
    f32x4 acc[8];
#pragma unroll
    for (int f = 0; f < 8; f++) acc[f] = (f32x4){0.f, 0.f, 0.f, 0.f};
    f32x4 accs = (f32x4){0.f, 0.f, 0.f, 0.f};   // row-sum accumulator
    short8 ones8;
#pragma unroll
    for (int e = 0; e < 8; e++) ones8[e] = (short)0x3F80;   // bf16 1.0

    // stage s2 once (waves 0-3: 64 chunks of 16B each)
    if (wave < 4) {
        gload_lds16(s2r + (size_t)(wave * 64 + lane) * 4, &ls2[wave * 256]);
    }
    __syncthreads();

    for (int j0 = 0; j0 < 1024; j0 += 32) {
        int jb = j0 + lg * 8;
        f32x4 t0 = *(const f32x4*)(&ls2[jb]);
        f32x4 t1 = *(const f32x4*)(&ls2[jb + 4]);
        unsigned bits = (unsigned)(abrow[j0 >> 6] >> ((j0 & 32) + lg * 8)) & 0xFFu;
        float pv[8];
#pragma unroll
        for (int e = 0; e < 8; e++) {
            float sv = e < 4 ? t0[e] : t1[e & 3];
            float ee = s1i + sv;
            ee = fmaxf(ee, ALPHA * ee);
            float p = fexp2(ee);
            pv[e] = ((bits >> e) & 1) ? p : 0.f;
        }
        int4v pw;
#pragma unroll
        for (int w = 0; w < 4; w++) {
            int d;
            asm("v_cvt_pk_bf16_f32 %0, %1, %2"
                : "=v"(d) : "v"(pv[2 * w]), "v"(pv[2 * w + 1]));
            pw[w] = d;
        }
        short8 pb = __builtin_bit_cast(short8, pw);
        accs = __builtin_amdgcn_mfma_f32_16x16x32_bf16(ones8, pb, accs, 0, 0, 0);
#pragma unroll
        for (int fm = 0; fm < 8; fm++) {
            short8 af = *(const short8*)(hlane + (size_t)(fm << 4) * 1024 + j0);
            acc[fm] = __builtin_amdgcn_mfma_f32_16x16x32_bf16(af, pb, acc[fm], 0, 0, 0);
        }
    }
    // row-sum for i = ic sits in every row of the ones-MFMA output (col = lr)
    float rdi = 1.f / accs[0];
    size_t orow = ((size_t)(b << 10) + ic) * 1024 + h * 128;
#pragma unroll
    for (int fm = 0; fm < 8; fm++) {
        int ob = (fm << 4) + lg * 4;
        short4v st;
#pragma unroll
        for (int r = 0; r < 4; r++) {
            float x = acc[fm][r] * rdi;
            x = x > 0.f ? x : expm1f(x);
            st[r] = f2bf(x);
        }
        *(short4v*)(out + orow + ob) = st;
    }
}

// ---------------- layer-2 attention, GATHERED rows, fused s1/s2 ----------------
// s2 quarter computed per wave into LDS; s1 for 16 nodes via octet partials.
__global__ __launch_bounds__(256) void k_attn2g(
        const short* __restrict__ h2t, const unsigned* __restrict__ adjb,
        const float* __restrict__ a1, const float* __restrict__ a2,
        const int* __restrict__ cidx, float* __restrict__ ghat) {
    int tile = blockIdx.x;      // 0..2
    int b = blockIdx.y;         // 0..7
    int tid = threadIdx.x, wave = tid >> 6, lane = tid & 63;
    int lr = lane & 15, lg = lane >> 4;

    __shared__ int nodes[16];
    __shared__ float ss1[16];
    __shared__ float sp1[16][17];
    __shared__ float ls2q[1024];
    __shared__ float sps[4][16];
    __shared__ float sacc[4][16][129];

    const short* hb = h2t + (size_t)b * 131072;

    if (tid < 16) {
        int pos = tile * 16 + tid;
        int nd0 = 0;
        if (pos >= 1 && pos <= 32) nd0 = cidx[b * 32 + pos - 1];
        nodes[tid] = nd0;
    }
    // s2 for this wave's j-quarter (fp32 accum, LOG2E-scaled)
    {
        int j4 = wave * 256 + lane * 4;
        const short* base = hb + j4;
        f32x4 a2v = {0.f, 0.f, 0.f, 0.f};
#pragma unroll 8
        for (int o = 0; o < 128; o++) {
            short4v v = *(const short4v*)(base + ((size_t)o << 10));
            float w2 = a2[o];
#pragma unroll
            for (int r = 0; r < 4; r++) a2v[r] += b2f(v[r]) * w2;
        }
#pragma unroll
        for (int r = 0; r < 4; r++) a2v[r] *= LOG2E;
        *(f32x4*)(&ls2q[j4]) = a2v;
    }
    __syncthreads();
    // s1 for the 16 gathered nodes: thread t -> node t&15, o-octet t>>4
    {
        int nd1 = nodes[tid & 15];
        int oc = tid >> 4;
        float p1 = 0.f;
#pragma unroll
        for (int oo = 0; oo < 8; oo++) {
            int o = oc * 8 + oo;
            p1 += b2f(hb[((size_t)o << 10) + nd1]) * a1[o];
        }
        sp1[oc][tid & 15] = p1;
    }
    __syncthreads();
    if (tid < 16) {
        float s = 0.f;
#pragma unroll
        for (int oc = 0; oc < 16; oc++) s += sp1[oc][tid];
        ss1[tid] = s * LOG2E;
    }
    __syncthreads();

    int nd = nodes[lr];
    float s1i = ss1[lr];
    const unsigned long long* abrow =
        (const unsigned long long*)(adjb + ((size_t)(b << 10) + nd) * 32);
    f32x4 acc[8];
#pragma unroll
    for (int f = 0; f < 8; f++) acc[f] = (f32x4){0.f, 0.f, 0.f, 0.f};
    float psum = 0.f;

    for (int j0 = wave * 256; j0 < wave * 256 + 256; j0 += 32) {
        int jb = j0 + lg * 8;
        f32x4 t0 = *(const f32x4*)(&ls2q[jb]);
        f32x4 t1 = *(const f32x4*)(&ls2q[jb + 4]);
        unsigned bits = (unsigned)(abrow[j0 >> 6] >> ((j0 & 32) + lg * 8)) & 0xFFu;
        short8 pb;
#pragma unroll
        for (int e = 0; e < 8; e++) {
            float sv = e < 4 ? t0[e] : t1[e & 3];
            float ee = s1i + sv;
            ee = fmaxf(ee, ALPHA * ee);
            float p = fexp2(ee);
            p = ((bits >> e) & 1) ? p : 0.f;
            psum += p;
            pb[e] = f2bf(p);
        }
#pragma unroll
        for (int fm = 0; fm < 8; fm++) {
            short8 af = *(const short8*)(hb + (size_t)(fm * 16 + lr) * 1024 + jb);
            acc[fm] = __builtin_amdgcn_mfma_f32_16x16x32_bf16(af, pb, acc[fm], 0, 0, 0);
        }
    }
    psum += __shfl_xor(psum, 16);
    psum += __shfl_xor(psum, 32);
    if (lg == 0) sps[wave][lr] = psum;
#pragma unroll
    for (int fm = 0; fm < 8; fm++)
#pragma unroll
        for (int r = 0; r < 4; r++)
            sacc[wave][lr][fm * 16 + lg * 4 + r] = acc[fm][r];
    __syncthreads();
    for (int e = tid; e < 2048; e += 256) {
        int li = e >> 7, o = e & 127;
        float sum = sps[0][li] + sps[1][li] + sps[2][li] + sps[3][li];
        float v = (sacc[0][li][o] + sacc[1][li][o] + sacc[2][li][o] + sacc[3][li][o]) / sum;
        v = v > 0.f ? v : expm1f(v);
        ghat[((size_t)b * 48 + tile * 16 + li) * 128 + o] = v;
    }
}

// ---------------- K/V projections, gload_lds-staged weight slices --------------
__global__ __launch_bounds__(256) void k_qkv(
        const float* __restrict__ ghat,
        const float* __restrict__ wk, const float* __restrict__ bk,
        const float* __restrict__ wvp, const float* __restrict__ bv,
        float* __restrict__ Kp, float* __restrict__ Vp) {
    int b = blockIdx.y, rg = blockIdx.x & 7, o0 = (blockIdx.x >> 3) * 64;
    int t = threadIdx.x, wvi = t >> 6, ln = t & 63;
    __shared__ float sx[4][128];
    __shared__ float sWk[128 * 64], sWv[128 * 64];

    if (wvi < 2) {
        int cb = wvi * 64;
        gload_lds16(ghat + ((size_t)b * 48 + 1 + rg * 4) * 128 + (size_t)(cb + ln) * 4,
                    (float*)sx + cb * 4);
    }
#pragma unroll
    for (int s = 0; s < 8; s++) {
        int cb = s * 256 + wvi * 64;
        int q = cb + ln, rw = q >> 4, c4 = q & 15;
        gload_lds16(wk  + (size_t)rw * 128 + o0 + c4 * 4, &sWk[cb * 4]);
        gload_lds16(wvp + (size_t)rw * 128 + o0 + c4 * 4, &sWv[cb * 4]);
    }
    __syncthreads();
    int o = o0 + ln;
    float ka = bk[o], va = bv[o];
#pragma unroll 32
    for (int c = 0; c < 128; c++) {
        float x = sx[wvi][c];
        ka += x * sWk[c * 64 + ln];
        va += x * sWv[c * 64 + ln];
    }
    int r = rg * 4 + wvi;
    Kp[((size_t)b * 32 + r) * 128 + o] = ka;
    Vp[((size_t)b * 32 + r) * 128 + o] = va;
}

// ---------------- tail: Qproj + MHA + wo + p1 + LN + relu -> tvec --------------
__global__ __launch_bounds__(256) void k_tail(
        const float* __restrict__ ghat, const float* __restrict__ Kp,
        const float* __restrict__ Vp,
        const float* __restrict__ wq, const float* __restrict__ bq,
        const float* __restrict__ wo, const float* __restrict__ bo,
        const float* __restrict__ p1w, const float* __restrict__ p1b,
        const float* __restrict__ lng, const float* __restrict__ lnb,
        float* __restrict__ tvec) {
    int b = blockIdx.x, t = threadIdx.x;
    int wvi = t >> 6, ln = t & 63;
    __shared__ float sq[128], sQ[128], sK[32][128], sV[32][128];
    __shared__ float sP[4][33], sO[128], sT[128], sZ[128];
    __shared__ float sred[2];
    __shared__ float sW[128 * 128];

#pragma unroll
    for (int s = 0; s < 4; s++) {
        int cb = s * 256 + wvi * 64;
        gload_lds16(Kp + (size_t)b * 4096 + (size_t)(cb + ln) * 4, (float*)sK + cb * 4);
        gload_lds16(Vp + (size_t)b * 4096 + (size_t)(cb + ln) * 4, (float*)sV + cb * 4);
    }
#pragma unroll
    for (int s = 0; s < 16; s++) {
        int cb = s * 256 + wvi * 64;
        gload_lds16(wq + (size_t)(cb + ln) * 4, &sW[cb * 4]);
    }
    if (t < 128) sq[t] = ghat[(size_t)b * 48 * 128 + t];
    __syncthreads();
    if (t < 128) {
        float a0 = 0.f, a1 = 0.f, a2 = 0.f, a3 = 0.f;
#pragma unroll
        for (int c = 0; c < 128; c += 4) {
            a0 += sq[c]     * sW[c * 128 + t];
            a1 += sq[c + 1] * sW[(c + 1) * 128 + t];
            a2 += sq[c + 2] * sW[(c + 2) * 128 + t];
            a3 += sq[c + 3] * sW[(c + 3) * 128 + t];
        }
        sQ[t] = bq[t] + ((a0 + a1) + (a2 + a3));
    }
    __syncthreads();
#pragma unroll
    for (int s = 0; s < 16; s++) {
        int cb = s * 256 + wvi * 64;
        gload_lds16(wo + (size_t)(cb + ln) * 4, &sW[cb * 4]);
    }
    if (t < 128) {
        int hh = t >> 5, jj = t & 31;
        float s = 0.f;
#pragma unroll
        for (int d = 0; d < 32; d++) s += sQ[hh * 32 + d] * sK[jj][hh * 32 + d];
        s *= 0.17677669529663687f;
        float m = s;
#pragma unroll
        for (int off = 16; off > 0; off >>= 1) m = fmaxf(m, __shfl_xor(m, off, 32));
        float p = __expf(s - m);
        float sum = p;
#pragma unroll
        for (int off = 16; off > 0; off >>= 1) sum += __shfl_xor(sum, off, 32);
        sP[hh][jj] = p / sum;
    }
    __syncthreads();
    if (t < 128) {
        int hh = t >> 5;
        float s = 0.f;
#pragma unroll
        for (int jj = 0; jj < 32; jj++) s += sP[hh][jj] * sV[jj][t];
        sO[t] = s;
    }
    __syncthreads();
    if (t < 128) {
        float a0 = 0.f, a1 = 0.f, a2 = 0.f, a3 = 0.f;
#pragma unroll
        for (int c = 0; c < 128; c += 4) {
            a0 += sO[c]     * sW[c * 128 + t];
            a1 += sO[c + 1] * sW[(c + 1) * 128 + t];
            a2 += sO[c + 2] * sW[(c + 2) * 128 + t];
            a3 += sO[c + 3] * sW[(c + 3) * 128 + t];
        }
        sT[t] = bo[t] + ((a0 + a1) + (a2 + a3));
    }
    __syncthreads();
#pragma unroll
    for (int s = 0; s < 16; s++) {
        int cb = s * 256 + wvi * 64;
        gload_lds16(p1w + (size_t)(cb + ln) * 4, &sW[cb * 4]);
    }
    __syncthreads();
    if (t < 128) {
        float a0 = 0.f, a1 = 0.f, a2 = 0.f, a3 = 0.f;
#pragma unroll
        for (int c = 0; c < 128; c += 4) {
            a0 += sT[c]     * sW[c * 128 + t];
            a1 += sT[c + 1] * sW[(c + 1) * 128 + t];
            a2 += sT[c + 2] * sW[(c + 2) * 128 + t];
            a3 += sT[c + 3] * sW[(c + 3) * 128 + t];
        }
        sZ[t] = p1b[t] + ((a0 + a1) + (a2 + a3));
    }
    __syncthreads();
    if (t < 64) {
        float v = sZ[t] + sZ[t + 64];
#pragma unroll
        for (int off = 32; off > 0; off >>= 1) v += __shfl_xor(v, off);
        if (t == 0) sred[0] = v * (1.f / 128.f);
    }
    __syncthreads();
    float mu = sred[0];
    if (t < 64) {
        float d1 = sZ[t] - mu, d2 = sZ[t + 64] - mu;
        float v = d1 * d1 + d2 * d2;
#pragma unroll
        for (int off = 32; off > 0; off >>= 1) v += __shfl_xor(v, off);
        if (t == 0) sred[1] = v * (1.f / 128.f);
    }
    __syncthreads();
    float rstd = rsqrtf(sred[1] + 1e-5f);
    if (t < 128) {
        float z = (sZ[t] - mu) * rstd * lng[t] + lnb[t];
        tvec[b * 128 + t] = fmaxf(z, 0.f);
    }
}

// ---------------- p2 projection: 48 blocks, gload_lds weight tiles -------------
__global__ __launch_bounds__(256) void k_p2(
        const float* __restrict__ tvec, const float* __restrict__ p2w,
        const float* __restrict__ p2b, float* __restrict__ out) {
    int jj0 = blockIdx.x * 128, b = blockIdx.y;
    int t = threadIdx.x, wvi = t >> 6, ln = t & 63;
    __shared__ float sT[128];
    __shared__ float sW[128 * 128];

#pragma unroll
    for (int s = 0; s < 16; s++) {
        int cb = s * 256 + wvi * 64;
        int q = cb + ln, c = q >> 5, c4 = q & 31;
        gload_lds16(p2w + (size_t)c * 768 + jj0 + c4 * 4, &sW[cb * 4]);
    }
    if (t < 128) sT[t] = tvec[b * 128 + t];
    __syncthreads();
    if (t < 128) {
        float a0 = 0.f, a1 = 0.f, a2 = 0.f, a3 = 0.f;
#pragma unroll
        for (int c = 0; c < 128; c += 4) {
            a0 += sT[c]     * sW[c * 128 + t];
            a1 += sT[c + 1] * sW[(c + 1) * 128 + t];
            a2 += sT[c + 2] * sW[(c + 2) * 128 + t];
            a3 += sT[c + 3] * sW[(c + 3) * 128 + t];
        }
        out[b * 768 + jj0 + t] = p2b[jj0 + t] + ((a0 + a1) + (a2 + a3));
    }
}

extern "C" void kernel_launch(void* const* d_in, const int* in_sizes, int n_in,
                              void* d_out, int out_size, void* d_ws, size_t ws_size,
                              hipStream_t stream) {
    const float* x   = (const float*)d_in[0];
    const int*  adj  = (const int*)d_in[1];
    const int*  cidx = (const int*)d_in[2];
    const float* W1  = (const float*)d_in[3];
    const float* a11 = (const float*)d_in[4];
    const float* a21 = (const float*)d_in[5];
    const float* W2  = (const float*)d_in[6];
    const float* a12 = (const float*)d_in[7];
    const float* a22 = (const float*)d_in[8];
    const float* wq = (const float*)d_in[9];  const float* bq = (const float*)d_in[10];
    const float* wk = (const float*)d_in[11]; const float* bk = (const float*)d_in[12];
    const float* wv = (const float*)d_in[13]; const float* bv = (const float*)d_in[14];
    const float* wo = (const float*)d_in[15]; const float* bo = (const float*)d_in[16];
    const float* p1w = (const float*)d_in[17]; const float* p1b = (const float*)d_in[18];
    const float* lng = (const float*)d_in[19]; const float* lnb = (const float*)d_in[20];
    const float* p2w = (const float*)d_in[21]; const float* p2b = (const float*)d_in[22];
    float* out = (float*)d_out;

    char* ws = (char*)d_ws;
    size_t off = 0;
    auto alloc = [&](size_t bytes) -> char* {
        char* p = ws + off;
        off = (off + bytes + 255) & ~(size_t)255;
        return p;
    };
    short* Xb   = (short*)alloc(8192ull * 768 * 2);
    short* W1T  = (short*)alloc(1024ull * 768 * 2);
    short* W2T  = (short*)alloc(128ull * 1024 * 2);
    unsigned* adjb = (unsigned*)alloc(8ull * 1024 * 32 * 4);
    short* h1t  = (short*)alloc(64ull * 128 * 1024 * 2);
    float* s1a  = (float*)alloc(64ull * 1024 * 4);
    float* s2a  = (float*)alloc(64ull * 1024 * 4);
    short* hcat = (short*)alloc(8192ull * 1024 * 2);
    short* h2t  = (short*)alloc(8ull * 128 * 1024 * 2);
    float* ghat = (float*)alloc(8ull * 48 * 128 * 4);
    float* Kp   = (float*)alloc(8ull * 32 * 128 * 4);
    float* Vp   = (float*)alloc(8ull * 32 * 128 * 4);
    float* tvec = (float*)alloc(8ull * 128 * 4);
    if (off > ws_size) return;

    // fused prep: adjbits | cast | w1t | w2t
    k_prep<<<42496, 256, 0, stream>>>(adj, adjb, x, Xb, W1, W1T, W2, W2T);

    // layer 1 (GEMM with fused s1/s2 epilogue)
    k_gemm_bt<<<dim3(64, 8), 256, 0, stream>>>(Xb, W1T, h1t, 768, 1024,
                                               a11, a21, s1a, s2a);
    k_attn1<<<dim3(8, 64), 512, 0, stream>>>(h1t, adjb, s1a, s2a, hcat);

    // layer 2 (GEMM full; attention fused with s1/s2 for gathered rows)
    k_gemm64<<<dim3(128, 2), 256, 0, stream>>>(hcat, W2T, h2t, 1024, 128);
    k_attn2g<<<dim3(3, 8), 256, 0, stream>>>(h2t, adjb, a12, a22, cidx, ghat);

    // tail
    k_qkv<<<dim3(16, 8), 256, 0, stream>>>(ghat, wk, bk, wv, bv, Kp, Vp);
    k_tail<<<8, 256, 0, stream>>>(ghat, Kp, Vp, wq, bq, wo, bo,
                                  p1w, p1b, lng, lnb, tvec);
    k_p2<<<dim3(6, 8), 256, 0, stream>>>(tvec, p2w, p2b, out);
}

// Round 20
// 136.844 us; speedup vs baseline: 1.7301x; 1.7301x over previous
//
#include <hip/hip_runtime.h>
#include <hip/hip_bf16.h>

#define ALPHA 0.2f
#define LOG2E 1.4426950408889634f

using short8  = __attribute__((ext_vector_type(8))) short;
using short4v = __attribute__((ext_vector_type(4))) short;
using f32x4   = __attribute__((ext_vector_type(4))) float;
using int4v   = __attribute__((ext_vector_type(4))) int;

static __device__ __forceinline__ float b2f(short s) {
    union { float f; unsigned u; } v; v.u = ((unsigned)(unsigned short)s) << 16; return v.f;
}
static __device__ __forceinline__ short f2bf(float f) {
    __hip_bfloat16 h = __float2bfloat16(f);
    return *reinterpret_cast<short*>(&h);
}
static __device__ __forceinline__ float fexp2(float x) {
    return __builtin_amdgcn_exp2f(x);          // v_exp_f32: D = 2^S0
}
static __device__ __forceinline__ void gload_lds16(const void* g, void* l) {
    __builtin_amdgcn_global_load_lds(
        (const __attribute__((address_space(1))) unsigned*)g,
        (__attribute__((address_space(3))) unsigned*)l, 16, 0, 0);
}

// ---------------- fused prep: adjbits | cast_x | w1t | w2t ----------------------
__global__ __launch_bounds__(256) void k_prep(
        const int* __restrict__ adj, unsigned* __restrict__ adjb,
        const float* __restrict__ x, short* __restrict__ xb,
        const float* __restrict__ W1, short* __restrict__ W1T,
        const float* __restrict__ W2, short* __restrict__ W2T) {
    int bid = blockIdx.x, t = threadIdx.x;
    if (bid < 32768) {                       // adj int32 -> bit-packed
        int idx = bid * 256 + t;
        int lane = t & 63;
        unsigned long long m = __ballot(adj[idx] > 0);
        if ((lane & 31) == 0) adjb[idx >> 5] = (unsigned)(m >> (lane & 32));
    } else if (bid < 38912) {                // x f32 -> bf16 (x4)
        int idx = (bid - 32768) * 256 + t;
        f32x4 v = ((const f32x4*)x)[idx];
        short4v o;
        o[0] = f2bf(v[0]); o[1] = f2bf(v[1]); o[2] = f2bf(v[2]); o[3] = f2bf(v[3]);
        ((short4v*)xb)[idx] = o;
    } else if (bid < 41984) {                // W1T[n][k] = W1[h][k][o]
        int idx = (bid - 38912) * 256 + t;
        int n = idx / 768, k = idx - n * 768;
        int h = n >> 7, o = n & 127;
        W1T[idx] = f2bf(W1[(h * 768 + k) * 128 + o]);
    } else {                                 // W2T[n][k] = W2[0][k][n]
        int idx = (bid - 41984) * 256 + t;
        int n = idx >> 10, k = idx & 1023;
        W2T[idx] = f2bf(W2[k * 128 + n]);
    }
}

// ---------------- bf16 MFMA GEMM 128x128, BK=64 pair, XCD-swz ------------------
// Layer-1 specialized: fused s1/s2 epilogue; coalesced C-store via LDS bounce.
__global__ __launch_bounds__(256) void k_gemm_bt(
        const short* __restrict__ A, const short* __restrict__ Bt,
        short* __restrict__ Ct, int K, int Ncols,
        const float* __restrict__ a1, const float* __restrict__ a2,
        float* __restrict__ s1, float* __restrict__ s2) {
    int tid = threadIdx.x, wave = tid >> 6, lane = tid & 63;
    int lr = lane & 15, lg = lane >> 4;
    int flat = blockIdx.y * gridDim.x + blockIdx.x;
    int chunkw = (gridDim.x * gridDim.y) >> 3;
    int swz = (flat & 7) * chunkw + (flat >> 3);
    int bx = swz % gridDim.x, by = swz / gridDim.x;
    int m0 = bx * 128, n0 = by * 128;
    int wm = (wave >> 1) * 64, wn = (wave & 1) * 64;
    __shared__ short lsA[2][128 * 64], lsB[2][128 * 64];
    __shared__ float sred1[2][128], sred2[2][128];
    f32x4 acc[4][4];
#pragma unroll
    for (int i = 0; i < 4; i++)
#pragma unroll
        for (int j = 0; j < 4; j++) acc[i][j] = (f32x4){0.f, 0.f, 0.f, 0.f};

    auto stage = [&](int bufsel, int k0) {
#pragma unroll
        for (int s = 0; s < 4; s++) {
            int chunk = s * 256 + tid;          // 1024 chunks of 16B per matrix
            int r = chunk >> 3, c = chunk & 7;
            int csrc = c ^ (r & 7);             // inverse-swizzled source
            gload_lds16(A + (size_t)(m0 + r) * K + k0 + csrc * 8, &lsA[bufsel][chunk * 8]);
            gload_lds16(Bt + (size_t)(n0 + r) * K + k0 + csrc * 8, &lsB[bufsel][chunk * 8]);
        }
    };
    auto compute = [&](const short* la, const short* lb) {
#pragma unroll
        for (int kk = 0; kk < 2; kk++) {
            short8 a[4], bb[4];
#pragma unroll
            for (int f = 0; f < 4; f++) {
                int ra = wm + f * 16 + lr, rb = wn + f * 16 + lr;
                a[f]  = *(const short8*)(la + ra * 64 + (((kk * 4 + lg) ^ (ra & 7)) * 8));
                bb[f] = *(const short8*)(lb + rb * 64 + (((kk * 4 + lg) ^ (rb & 7)) * 8));
            }
#pragma unroll
            for (int fm = 0; fm < 4; fm++)
#pragma unroll
                for (int fn = 0; fn < 4; fn++)
                    acc[fm][fn] = __builtin_amdgcn_mfma_f32_16x16x32_bf16(a[fm], bb[fn], acc[fm][fn], 0, 0, 0);
        }
    };
    stage(0, 0);
    __syncthreads();
    for (int k2 = 0; k2 < K; k2 += 128) {       // requires K % 128 == 0
        stage(1, k2 + 64);
        compute(lsA[0], lsB[0]);
        __syncthreads();
        if (k2 + 128 < K) stage(0, k2 + 128);
        compute(lsA[1], lsB[1]);
        __syncthreads();
    }
    // C-store via LDS bounce: stg[n_local][i4 swizzled] -> 256B-contiguous writes
    short* stg = &lsA[0][0];                    // 32KB, free after K-loop
#pragma unroll
    for (int fm = 0; fm < 4; fm++) {
#pragma unroll
        for (int fn = 0; fn < 4; fn++) {
            int nl = wn + fn * 16 + lr;
            int i4w = (wm + fm * 16 + lg * 4) >> 2;
            short4v st;
            st[0] = f2bf(acc[fm][fn][0]); st[1] = f2bf(acc[fm][fn][1]);
            st[2] = f2bf(acc[fm][fn][2]); st[3] = f2bf(acc[fm][fn][3]);
            *(short4v*)(stg + (nl * 32 + (i4w ^ (nl & 31))) * 4) = st;
        }
    }
    __syncthreads();
    size_t gbase = ((size_t)(m0 >> 10) * Ncols + n0) * 1024 + (m0 & 1023);
#pragma unroll
    for (int it = 0; it < 8; it++) {
        int idx8 = it * 256 + tid;              // 2048 units of 16B
        int nl = idx8 >> 4, p = idx8 & 15;
        int i4a = 2 * p, i4b = 2 * p + 1;
        short4v lo = *(short4v*)(stg + (nl * 32 + (i4a ^ (nl & 31))) * 4);
        short4v hi = *(short4v*)(stg + (nl * 32 + (i4b ^ (nl & 31))) * 4);
        short8 v;
#pragma unroll
        for (int r = 0; r < 4; r++) { v[r] = lo[r]; v[r + 4] = hi[r]; }
        *(short8*)(Ct + gbase + (size_t)nl * 1024 + p * 8) = v;
    }
    // fused s1/s2 epilogue (layer 1 only: a1 != nullptr)
    if (a1 != nullptr) {
        int h = by;                              // n-block == head
        float av1[4], av2[4];
#pragma unroll
        for (int fn = 0; fn < 4; fn++) {
            int o = wn + fn * 16 + lr;
            av1[fn] = a1[h * 128 + o];
            av2[fn] = a2[h * 128 + o];
        }
        int wcol = wave & 1;
#pragma unroll
        for (int fm = 0; fm < 4; fm++)
#pragma unroll
            for (int r = 0; r < 4; r++) {
                float v1 = acc[fm][0][r] * av1[0] + acc[fm][1][r] * av1[1]
                         + acc[fm][2][r] * av1[2] + acc[fm][3][r] * av1[3];
                float v2 = acc[fm][0][r] * av2[0] + acc[fm][1][r] * av2[1]
                         + acc[fm][2][r] * av2[2] + acc[fm][3][r] * av2[3];
#pragma unroll
                for (int off = 1; off < 16; off <<= 1) {
                    v1 += __shfl_xor(v1, off);
                    v2 += __shfl_xor(v2, off);
                }
                if (lr == 0) {
                    int il = wm + fm * 16 + lg * 4 + r;
                    sred1[wcol][il] = v1;
                    sred2[wcol][il] = v2;
                }
            }
        __syncthreads();
        if (tid < 128) {
            int b = m0 >> 10;
            int irow = (b * 8 + h) * 1024 + (m0 & 1023) + tid;
            s1[irow] = (sred1[0][tid] + sred1[1][tid]) * LOG2E;
            s2[irow] = (sred2[0][tid] + sred2[1][tid]) * LOG2E;
        }
    }
}

// ---------------- bf16 MFMA GEMM 64x64 (layer-2) -------------------------------
__global__ __launch_bounds__(256) void k_gemm64(
        const short* __restrict__ A, const short* __restrict__ Bt,
        short* __restrict__ Ct, int K, int Ncols) {
    int tid = threadIdx.x, wave = tid >> 6, lane = tid & 63;
    int lr = lane & 15, lg = lane >> 4;
    int flat = blockIdx.y * gridDim.x + blockIdx.x;
    int chunkw = (gridDim.x * gridDim.y) >> 3;
    int swz = (flat & 7) * chunkw + (flat >> 3);
    int bx = swz % gridDim.x, by = swz / gridDim.x;
    int m0 = bx * 64, n0 = by * 64;
    int wm = (wave >> 1) * 32, wn = (wave & 1) * 32;
    __shared__ short lsA[2][64 * 32], lsB[2][64 * 32];
    f32x4 acc[2][2];
#pragma unroll
    for (int i = 0; i < 2; i++)
#pragma unroll
        for (int j = 0; j < 2; j++) acc[i][j] = (f32x4){0.f, 0.f, 0.f, 0.f};

    auto stage = [&](int bufsel, int k0) {
        int r = tid >> 2, c = tid & 3;
        int csrc = c ^ (r & 3);
        int base = (wave * 64) * 8;
        gload_lds16(A + (size_t)(m0 + r) * K + k0 + csrc * 8, &lsA[bufsel][base]);
        gload_lds16(Bt + (size_t)(n0 + r) * K + k0 + csrc * 8, &lsB[bufsel][base]);
    };
    stage(0, 0);
    __syncthreads();
    int buf = 0;
    for (int k0 = 0; k0 < K; k0 += 32) {
        if (k0 + 32 < K) stage(buf ^ 1, k0 + 32);
        short8 a[2], bb[2];
#pragma unroll
        for (int f = 0; f < 2; f++) {
            int ra = wm + f * 16 + lr, rb = wn + f * 16 + lr;
            a[f]  = *(const short8*)(&lsA[buf][ra * 32 + ((lg ^ (ra & 3)) * 8)]);
            bb[f] = *(const short8*)(&lsB[buf][rb * 32 + ((lg ^ (rb & 3)) * 8)]);
        }
#pragma unroll
        for (int fm = 0; fm < 2; fm++)
#pragma unroll
            for (int fn = 0; fn < 2; fn++)
                acc[fm][fn] = __builtin_amdgcn_mfma_f32_16x16x32_bf16(a[fm], bb[fn], acc[fm][fn], 0, 0, 0);
        __syncthreads();
        buf ^= 1;
    }
#pragma unroll
    for (int fm = 0; fm < 2; fm++) {
        int mb = m0 + wm + fm * 16 + lg * 4;
        size_t obase = ((size_t)(mb >> 10) * Ncols) * 1024 + (mb & 1023);
#pragma unroll
        for (int fn = 0; fn < 2; fn++) {
            int n = n0 + wn + fn * 16 + lr;
            short4v st;
            st[0] = f2bf(acc[fm][fn][0]); st[1] = f2bf(acc[fm][fn][1]);
            st[2] = f2bf(acc[fm][fn][2]); st[3] = f2bf(acc[fm][fn][3]);
            *(short4v*)(Ct + obase + (size_t)n * 1024) = st;
        }
    }
}

// ---------------- GAT layer-1 attention: 8 waves x 16 i, s2 in LDS -------------
// LDS-staged h (dbuf, swizzled) — R19 proved direct-L2 reads are latency-bound
// (7.7 TB/s effective, VALUBusy 19%); async gload_lds staging is the win.
// psum via ones-MFMA; grid (8, 64) XCD-swizzled (bh panels L2-resident).
__global__ __launch_bounds__(512) void k_attn1(
        const short* __restrict__ ht, const unsigned* __restrict__ adjb,
        const float* __restrict__ s1, const float* __restrict__ s2,
        short* __restrict__ out) {
    int flat = blockIdx.y * 8 + blockIdx.x;
    int swz = (flat & 7) * 64 + (flat >> 3);    // 512 blocks: bijective
    int bh = swz >> 3, bxi = swz & 7;
    int b = bh >> 3, h = bh & 7;
    int tid = threadIdx.x, wave = tid >> 6, lane = tid & 63;
    int lr = lane & 15, lg = lane >> 4;
    int ic = bxi * 128 + wave * 16 + lr;
    int row = bh * 1024 + ic;
    float s1i = s1[row];                        // pre-scaled by log2e
    const unsigned long long* abrow =
        (const unsigned long long*)(adjb + ((size_t)(b << 10) + ic) * 32);
    const float* s2r = s2 + bh * 1024;
    const short* hbase = ht + (size_t)bh * 131072;

    __shared__ short lsh[2][16384];   // [128 o][128 j] bf16, chunk-XOR swizzled
    __shared__ float ls2[1024];       // staged s2 row (4KB)
    f32x4 acc[8];
#pragma unroll
    for (int f = 0; f < 8; f++) acc[f] = (f32x4){0.f, 0.f, 0.f, 0.f};
    f32x4 accs = (f32x4){0.f, 0.f, 0.f, 0.f};   // row-sum accumulator
    short8 ones8;
#pragma unroll
    for (int e = 0; e < 8; e++) ones8[e] = (short)0x3F80;   // bf16 1.0

    auto stage = [&](int bufsel, int j0) {
#pragma unroll
        for (int s = 0; s < 4; s++) {
            int chunk = s * 512 + tid;       // 2048 chunks of 16B
            int r = chunk >> 4, c = chunk & 15;
            int csrc = c ^ (r & 15);         // inverse-swizzle the SOURCE
            gload_lds16(hbase + (size_t)r * 1024 + j0 + csrc * 8,
                        &lsh[bufsel][chunk * 8]);
        }
    };
    auto compute = [&](const short* ls, int j0) {
        unsigned long long aw0 = abrow[j0 >> 6], aw1 = abrow[(j0 >> 6) + 1];
#pragma unroll
        for (int kk = 0; kk < 4; kk++) {
            int jb = j0 + kk * 32 + lg * 8;
            f32x4 t0 = *(const f32x4*)(&ls2[jb]);
            f32x4 t1 = *(const f32x4*)(&ls2[jb + 4]);
            unsigned long long aw = (kk < 2) ? aw0 : aw1;
            unsigned bits = (unsigned)(aw >> ((kk & 1) * 32 + lg * 8)) & 0xFFu;
            float pv[8];
#pragma unroll
            for (int e = 0; e < 8; e++) {
                float sv = e < 4 ? t0[e] : t1[e & 3];
                float ee = s1i + sv;
                ee = fmaxf(ee, ALPHA * ee);
                float p = fexp2(ee);
                pv[e] = ((bits >> e) & 1) ? p : 0.f;
            }
            int4v pw;
#pragma unroll
            for (int w = 0; w < 4; w++) {
                int d;
                asm("v_cvt_pk_bf16_f32 %0, %1, %2"
                    : "=v"(d) : "v"(pv[2 * w]), "v"(pv[2 * w + 1]));
                pw[w] = d;
            }
            short8 pb = __builtin_bit_cast(short8, pw);
            accs = __builtin_amdgcn_mfma_f32_16x16x32_bf16(ones8, pb, accs, 0, 0, 0);
#pragma unroll
            for (int fm = 0; fm < 8; fm++) {
                int r = fm * 16 + lr;
                int ck = (kk * 4 + lg) ^ (r & 15);   // swizzled read
                short8 af = *(const short8*)(ls + r * 128 + ck * 8);
                acc[fm] = __builtin_amdgcn_mfma_f32_16x16x32_bf16(af, pb, acc[fm], 0, 0, 0);
            }
        }
    };

    // stage s2 once (waves 0-3: 64 chunks of 16B each)
    if (wave < 4) {
        gload_lds16(s2r + (size_t)(wave * 64 + lane) * 4, &ls2[wave * 256]);
    }
    stage(0, 0);
    __syncthreads();
    for (int t2 = 0; t2 < 1024; t2 += 256) {
        stage(1, t2 + 128);
        compute(lsh[0], t2);
        __syncthreads();
        if (t2 + 256 < 1024) stage(0, t2 + 256);
        compute(lsh[1], t2 + 128);
        __syncthreads();
    }
    // row-sum for i = ic sits in every row of the ones-MFMA output (col = lr)
    float rdi = 1.f / accs[0];
    size_t orow = ((size_t)(b << 10) + ic) * 1024 + h * 128;
#pragma unroll
    for (int fm = 0; fm < 8; fm++) {
        int ob = (fm << 4) + lg * 4;
        short4v st;
#pragma unroll
        for (int r = 0; r < 4; r++) {
            float x = acc[fm][r] * rdi;
            x = x > 0.f ? x : expm1f(x);
            st[r] = f2bf(x);
        }
        *(short4v*)(out + orow + ob) = st;
    }
}

// ---------------- layer-2 attention, GATHERED rows, fused s1/s2 ----------------
// s2 quarter computed per wave into LDS; s1 for 16 nodes via octet partials.
__global__ __launch_bounds__(256) void k_attn2g(
        const short* __restrict__ h2t, const unsigned* __restrict__ adjb,
        const float* __restrict__ a1, const float* __restrict__ a2,
        const int* __restrict__ cidx, float* __restrict__ ghat) {
    int tile = blockIdx.x;      // 0..2
    int b = blockIdx.y;         // 0..7
    int tid = threadIdx.x, wave = tid >> 6, lane = tid & 63;
    int lr = lane & 15, lg = lane >> 4;

    __shared__ int nodes[16];
    __shared__ float ss1[16];
    __shared__ float sp1[16][17];
    __shared__ float ls2q[1024];
    __shared__ float sps[4][16];
    __shared__ float sacc[4][16][129];

    const short* hb = h2t + (size_t)b * 131072;

    if (tid < 16) {
        int pos = tile * 16 + tid;
        int nd0 = 0;
        if (pos >= 1 && pos <= 32) nd0 = cidx[b * 32 + pos - 1];
        nodes[tid] = nd0;
    }
    // s2 for this wave's j-quarter (fp32 accum, LOG2E-scaled)
    {
        int j4 = wave * 256 + lane * 4;
        const short* base = hb + j4;
        f32x4 a2v = {0.f, 0.f, 0.f, 0.f};
#pragma unroll 8
        for (int o = 0; o < 128; o++) {
            short4v v = *(const short4v*)(base + ((size_t)o << 10));
            float w2 = a2[o];
#pragma unroll
            for (int r = 0; r < 4; r++) a2v[r] += b2f(v[r]) * w2;
        }
#pragma unroll
        for (int r = 0; r < 4; r++) a2v[r] *= LOG2E;
        *(f32x4*)(&ls2q[j4]) = a2v;
    }
    __syncthreads();
    // s1 for the 16 gathered nodes: thread t -> node t&15, o-octet t>>4
    {
        int nd1 = nodes[tid & 15];
        int oc = tid >> 4;
        float p1 = 0.f;
#pragma unroll
        for (int oo = 0; oo < 8; oo++) {
            int o = oc * 8 + oo;
            p1 += b2f(hb[((size_t)o << 10) + nd1]) * a1[o];
        }
        sp1[oc][tid & 15] = p1;
    }
    __syncthreads();
    if (tid < 16) {
        float s = 0.f;
#pragma unroll
        for (int oc = 0; oc < 16; oc++) s += sp1[oc][tid];
        ss1[tid] = s * LOG2E;
    }
    __syncthreads();

    int nd = nodes[lr];
    float s1i = ss1[lr];
    const unsigned long long* abrow =
        (const unsigned long long*)(adjb + ((size_t)(b << 10) + nd) * 32);
    f32x4 acc[8];
#pragma unroll
    for (int f = 0; f < 8; f++) acc[f] = (f32x4){0.f, 0.f, 0.f, 0.f};
    float psum = 0.f;

    for (int j0 = wave * 256; j0 < wave * 256 + 256; j0 += 32) {
        int jb = j0 + lg * 8;
        f32x4 t0 = *(const f32x4*)(&ls2q[jb]);
        f32x4 t1 = *(const f32x4*)(&ls2q[jb + 4]);
        unsigned bits = (unsigned)(abrow[j0 >> 6] >> ((j0 & 32) + lg * 8)) & 0xFFu;
        short8 pb;
#pragma unroll
        for (int e = 0; e < 8; e++) {
            float sv = e < 4 ? t0[e] : t1[e & 3];
            float ee = s1i + sv;
            ee = fmaxf(ee, ALPHA * ee);
            float p = fexp2(ee);
            p = ((bits >> e) & 1) ? p : 0.f;
            psum += p;
            pb[e] = f2bf(p);
        }
#pragma unroll
        for (int fm = 0; fm < 8; fm++) {
            short8 af = *(const short8*)(hb + (size_t)(fm * 16 + lr) * 1024 + jb);
            acc[fm] = __builtin_amdgcn_mfma_f32_16x16x32_bf16(af, pb, acc[fm], 0, 0, 0);
        }
    }
    psum += __shfl_xor(psum, 16);
    psum += __shfl_xor(psum, 32);
    if (lg == 0) sps[wave][lr] = psum;
#pragma unroll
    for (int fm = 0; fm < 8; fm++)
#pragma unroll
        for (int r = 0; r < 4; r++)
            sacc[wave][lr][fm * 16 + lg * 4 + r] = acc[fm][r];
    __syncthreads();
    for (int e = tid; e < 2048; e += 256) {
        int li = e >> 7, o = e & 127;
        float sum = sps[0][li] + sps[1][li] + sps[2][li] + sps[3][li];
        float v = (sacc[0][li][o] + sacc[1][li][o] + sacc[2][li][o] + sacc[3][li][o]) / sum;
        v = v > 0.f ? v : expm1f(v);
        ghat[((size_t)b * 48 + tile * 16 + li) * 128 + o] = v;
    }
}

// ---------------- K/V projections, gload_lds-staged weight slices --------------
__global__ __launch_bounds__(256) void k_qkv(
        const float* __restrict__ ghat,
        const float* __restrict__ wk, const float* __restrict__ bk,
        const float* __restrict__ wvp, const float* __restrict__ bv,
        float* __restrict__ Kp, float* __restrict__ Vp) {
    int b = blockIdx.y, rg = blockIdx.x & 7, o0 = (blockIdx.x >> 3) * 64;
    int t = threadIdx.x, wvi = t >> 6, ln = t & 63;
    __shared__ float sx[4][128];
    __shared__ float sWk[128 * 64], sWv[128 * 64];

    if (wvi < 2) {
        int cb = wvi * 64;
        gload_lds16(ghat + ((size_t)b * 48 + 1 + rg * 4) * 128 + (size_t)(cb + ln) * 4,
                    (float*)sx + cb * 4);
    }
#pragma unroll
    for (int s = 0; s < 8; s++) {
        int cb = s * 256 + wvi * 64;
        int q = cb + ln, rw = q >> 4, c4 = q & 15;
        gload_lds16(wk  + (size_t)rw * 128 + o0 + c4 * 4, &sWk[cb * 4]);
        gload_lds16(wvp + (size_t)rw * 128 + o0 + c4 * 4, &sWv[cb * 4]);
    }
    __syncthreads();
    int o = o0 + ln;
    float ka = bk[o], va = bv[o];
#pragma unroll 32
    for (int c = 0; c < 128; c++) {
        float x = sx[wvi][c];
        ka += x * sWk[c * 64 + ln];
        va += x * sWv[c * 64 + ln];
    }
    int r = rg * 4 + wvi;
    Kp[((size_t)b * 32 + r) * 128 + o] = ka;
    Vp[((size_t)b * 32 + r) * 128 + o] = va;
}

// ---------------- tail: Qproj + MHA + wo + p1 + LN + relu -> tvec --------------
__global__ __launch_bounds__(256) void k_tail(
        const float* __restrict__ ghat, const float* __restrict__ Kp,
        const float* __restrict__ Vp,
        const float* __restrict__ wq, const float* __restrict__ bq,
        const float* __restrict__ wo, const float* __restrict__ bo,
        const float* __restrict__ p1w, const float* __restrict__ p1b,
        const float* __restrict__ lng, const float* __restrict__ lnb,
        float* __restrict__ tvec) {
    int b = blockIdx.x, t = threadIdx.x;
    int wvi = t >> 6, ln = t & 63;
    __shared__ float sq[128], sQ[128], sK[32][128], sV[32][128];
    __shared__ float sP[4][33], sO[128], sT[128], sZ[128];
    __shared__ float sred[2];
    __shared__ float sW[128 * 128];

#pragma unroll
    for (int s = 0; s < 4; s++) {
        int cb = s * 256 + wvi * 64;
        gload_lds16(Kp + (size_t)b * 4096 + (size_t)(cb + ln) * 4, (float*)sK + cb * 4);
        gload_lds16(Vp + (size_t)b * 4096 + (size_t)(cb + ln) * 4, (float*)sV + cb * 4);
    }
#pragma unroll
    for (int s = 0; s < 16; s++) {
        int cb = s * 256 + wvi * 64;
        gload_lds16(wq + (size_t)(cb + ln) * 4, &sW[cb * 4]);
    }
    if (t < 128) sq[t] = ghat[(size_t)b * 48 * 128 + t];
    __syncthreads();
    if (t < 128) {
        float a0 = 0.f, a1 = 0.f, a2 = 0.f, a3 = 0.f;
#pragma unroll
        for (int c = 0; c < 128; c += 4) {
            a0 += sq[c]     * sW[c * 128 + t];
            a1 += sq[c + 1] * sW[(c + 1) * 128 + t];
            a2 += sq[c + 2] * sW[(c + 2) * 128 + t];
            a3 += sq[c + 3] * sW[(c + 3) * 128 + t];
        }
        sQ[t] = bq[t] + ((a0 + a1) + (a2 + a3));
    }
    __syncthreads();
#pragma unroll
    for (int s = 0; s < 16; s++) {
        int cb = s * 256 + wvi * 64;
        gload_lds16(wo + (size_t)(cb + ln) * 4, &sW[cb * 4]);
    }
    if (t < 128) {
        int hh = t >> 5, jj = t & 31;
        float s = 0.f;
#pragma unroll
        for (int d = 0; d < 32; d++) s += sQ[hh * 32 + d] * sK[jj][hh * 32 + d];
        s *= 0.17677669529663687f;
        float m = s;
#pragma unroll
        for (int off = 16; off > 0; off >>= 1) m = fmaxf(m, __shfl_xor(m, off, 32));
        float p = __expf(s - m);
        float sum = p;
#pragma unroll
        for (int off = 16; off > 0; off >>= 1) sum += __shfl_xor(sum, off, 32);
        sP[hh][jj] = p / sum;
    }
    __syncthreads();
    if (t < 128) {
        int hh = t >> 5;
        float s = 0.f;
#pragma unroll
        for (int jj = 0; jj < 32; jj++) s += sP[hh][jj] * sV[jj][t];
        sO[t] = s;
    }
    __syncthreads();
    if (t < 128) {
        float a0 = 0.f, a1 = 0.f, a2 = 0.f, a3 = 0.f;
#pragma unroll
        for (int c = 0; c < 128; c += 4) {
            a0 += sO[c]     * sW[c * 128 + t];
            a1 += sO[c + 1] * sW[(c + 1) * 128 + t];
            a2 += sO[c + 2] * sW[(c + 2) * 128 + t];
            a3 += sO[c + 3] * sW[(c + 3) * 128 + t];
        }
        sT[t] = bo[t] + ((a0 + a1) + (a2 + a3));
    }
    __syncthreads();
#pragma unroll
    for (int s = 0; s < 16; s++) {
        int cb = s * 256 + wvi * 64;
        gload_lds16(p1w + (size_t)(cb + ln) * 4, &sW[cb * 4]);
    }
    __syncthreads();
    if (t < 128) {
        float a0 = 0.f, a1 = 0.f, a2 = 0.f, a3 = 0.f;
#pragma unroll
        for (int c = 0; c < 128; c += 4) {
            a0 += sT[c]     * sW[c * 128 + t];
            a1 += sT[c + 1] * sW[(c + 1) * 128 + t];
            a2 += sT[c + 2] * sW[(c + 2) * 128 + t];
            a3 += sT[c + 3] * sW[(c + 3) * 128 + t];
        }
        sZ[t] = p1b[t] + ((a0 + a1) + (a2 + a3));
    }
    __syncthreads();
    if (t < 64) {
        float v = sZ[t] + sZ[t + 64];
#pragma unroll
        for (int off = 32; off > 0; off >>= 1) v += __shfl_xor(v, off);
        if (t == 0) sred[0] = v * (1.f / 128.f);
    }
    __syncthreads();
    float mu = sred[0];
    if (t < 64) {
        float d1 = sZ[t] - mu, d2 = sZ[t + 64] - mu;
        float v = d1 * d1 + d2 * d2;
#pragma unroll
        for (int off = 32; off > 0; off >>= 1) v += __shfl_xor(v, off);
        if (t == 0) sred[1] = v * (1.f / 128.f);
    }
    __syncthreads();
    float rstd = rsqrtf(sred[1] + 1e-5f);
    if (t < 128) {
        float z = (sZ[t] - mu) * rstd * lng[t] + lnb[t];
        tvec[b * 128 + t] = fmaxf(z, 0.f);
    }
}

// ---------------- p2 projection: 48 blocks, gload_lds weight tiles -------------
__global__ __launch_bounds__(256) void k_p2(
        const float* __restrict__ tvec, const float* __restrict__ p2w,
        const float* __restrict__ p2b, float* __restrict__ out) {
    int jj0 = blockIdx.x * 128, b = blockIdx.y;
    int t = threadIdx.x, wvi = t >> 6, ln = t & 63;
    __shared__ float sT[128];
    __shared__ float sW[128 * 128];

#pragma unroll
    for (int s = 0; s < 16; s++) {
        int cb = s * 256 + wvi * 64;
        int q = cb + ln, c = q >> 5, c4 = q & 31;
        gload_lds16(p2w + (size_t)c * 768 + jj0 + c4 * 4, &sW[cb * 4]);
    }
    if (t < 128) sT[t] = tvec[b * 128 + t];
    __syncthreads();
    if (t < 128) {
        float a0 = 0.f, a1 = 0.f, a2 = 0.f, a3 = 0.f;
#pragma unroll
        for (int c = 0; c < 128; c += 4) {
            a0 += sT[c]     * sW[c * 128 + t];
            a1 += sT[c + 1] * sW[(c + 1) * 128 + t];
            a2 += sT[c + 2] * sW[(c + 2) * 128 + t];
            a3 += sT[c + 3] * sW[(c + 3) * 128 + t];
        }
        out[b * 768 + jj0 + t] = p2b[jj0 + t] + ((a0 + a1) + (a2 + a3));
    }
}

extern "C" void kernel_launch(void* const* d_in, const int* in_sizes, int n_in,
                              void* d_out, int out_size, void* d_ws, size_t ws_size,
                              hipStream_t stream) {
    const float* x   = (const float*)d_in[0];
    const int*  adj  = (const int*)d_in[1];
    const int*  cidx = (const int*)d_in[2];
    const float* W1  = (const float*)d_in[3];
    const float* a11 = (const float*)d_in[4];
    const float* a21 = (const float*)d_in[5];
    const float* W2  = (const float*)d_in[6];
    const float* a12 = (const float*)d_in[7];
    const float* a22 = (const float*)d_in[8];
    const float* wq = (const float*)d_in[9];  const float* bq = (const float*)d_in[10];
    const float* wk = (const float*)d_in[11]; const float* bk = (const float*)d_in[12];
    const float* wv = (const float*)d_in[13]; const float* bv = (const float*)d_in[14];
    const float* wo = (const float*)d_in[15]; const float* bo = (const float*)d_in[16];
    const float* p1w = (const float*)d_in[17]; const float* p1b = (const float*)d_in[18];
    const float* lng = (const float*)d_in[19]; const float* lnb = (const float*)d_in[20];
    const float* p2w = (const float*)d_in[21]; const float* p2b = (const float*)d_in[22];
    float* out = (float*)d_out;

    char* ws = (char*)d_ws;
    size_t off = 0;
    auto alloc = [&](size_t bytes) -> char* {
        char* p = ws + off;
        off = (off + bytes + 255) & ~(size_t)255;
        return p;
    };
    short* Xb   = (short*)alloc(8192ull * 768 * 2);
    short* W1T  = (short*)alloc(1024ull * 768 * 2);
    short* W2T  = (short*)alloc(128ull * 1024 * 2);
    unsigned* adjb = (unsigned*)alloc(8ull * 1024 * 32 * 4);
    short* h1t  = (short*)alloc(64ull * 128 * 1024 * 2);
    float* s1a  = (float*)alloc(64ull * 1024 * 4);
    float* s2a  = (float*)alloc(64ull * 1024 * 4);
    short* hcat = (short*)alloc(8192ull * 1024 * 2);
    short* h2t  = (short*)alloc(8ull * 128 * 1024 * 2);
    float* ghat = (float*)alloc(8ull * 48 * 128 * 4);
    float* Kp   = (float*)alloc(8ull * 32 * 128 * 4);
    float* Vp   = (float*)alloc(8ull * 32 * 128 * 4);
    float* tvec = (float*)alloc(8ull * 128 * 4);
    if (off > ws_size) return;

    // fused prep: adjbits | cast | w1t | w2t
    k_prep<<<42496, 256, 0, stream>>>(adj, adjb, x, Xb, W1, W1T, W2, W2T);

    // layer 1 (GEMM with fused s1/s2 epilogue)
    k_gemm_bt<<<dim3(64, 8), 256, 0, stream>>>(Xb, W1T, h1t, 768, 1024,
                                               a11, a21, s1a, s2a);
    k_attn1<<<dim3(8, 64), 512, 0, stream>>>(h1t, adjb, s1a, s2a, hcat);

    // layer 2 (GEMM full; attention fused with s1/s2 for gathered rows)
    k_gemm64<<<dim3(128, 2), 256, 0, stream>>>(hcat, W2T, h2t, 1024, 128);
    k_attn2g<<<dim3(3, 8), 256, 0, stream>>>(h2t, adjb, a12, a22, cidx, ghat);

    // tail
    k_qkv<<<dim3(16, 8), 256, 0, stream>>>(ghat, wk, bk, wv, bv, Kp, Vp);
    k_tail<<<8, 256, 0, stream>>>(ghat, Kp, Vp, wq, bq, wo, bo,
                                  p1w, p1b, lng, lnb, tvec);
    k_p2<<<dim3(6, 8), 256, 0, stream>>>(tvec, p2w, p2b, out);
}

// Round 21
// 132.600 us; speedup vs baseline: 1.7855x; 1.0320x over previous
//
#include <hip/hip_runtime.h>
#include <hip/hip_bf16.h>

#define ALPHA 0.2f
#define LOG2E 1.4426950408889634f

using short8  = __attribute__((ext_vector_type(8))) short;
using short4v = __attribute__((ext_vector_type(4))) short;
using f32x4   = __attribute__((ext_vector_type(4))) float;
using int4v   = __attribute__((ext_vector_type(4))) int;

static __device__ __forceinline__ float b2f(short s) {
    union { float f; unsigned u; } v; v.u = ((unsigned)(unsigned short)s) << 16; return v.f;
}
static __device__ __forceinline__ short f2bf(float f) {
    __hip_bfloat16 h = __float2bfloat16(f);
    return *reinterpret_cast<short*>(&h);
}
static __device__ __forceinline__ float fexp2(float x) {
    return __builtin_amdgcn_exp2f(x);          // v_exp_f32: D = 2^S0
}
static __device__ __forceinline__ void gload_lds16(const void* g, void* l) {
    __builtin_amdgcn_global_load_lds(
        (const __attribute__((address_space(1))) unsigned*)g,
        (__attribute__((address_space(3))) unsigned*)l, 16, 0, 0);
}

// ---------------- fused prep: adjbits | cast_x | LDS-tiled W transposes --------
// W1T/W2T now via 64x64 LDS tile transpose: both global sides coalesced
// (old path read stride-512B -> 16x over-fetch, ~50MB for 3.5MB of data).
__global__ __launch_bounds__(256) void k_prep(
        const int* __restrict__ adj, unsigned* __restrict__ adjb,
        const float* __restrict__ x, short* __restrict__ xb,
        const float* __restrict__ W1, short* __restrict__ W1T,
        const float* __restrict__ W2, short* __restrict__ W2T) {
    int bid = blockIdx.x, t = threadIdx.x;
    if (bid < 32768) {                       // adj int32 -> bit-packed
        int idx = bid * 256 + t;
        int lane = t & 63;
        unsigned long long m = __ballot(adj[idx] > 0);
        if ((lane & 31) == 0) adjb[idx >> 5] = (unsigned)(m >> (lane & 32));
    } else if (bid < 38912) {                // x f32 -> bf16 (x4)
        int idx = (bid - 32768) * 256 + t;
        f32x4 v = ((const f32x4*)x)[idx];
        short4v o;
        o[0] = f2bf(v[0]); o[1] = f2bf(v[1]); o[2] = f2bf(v[2]); o[3] = f2bf(v[3]);
        ((short4v*)xb)[idx] = o;
    } else {                                 // 64x64 tile transposes (224 tiles)
        __shared__ short tileT[64][65];
        int tb = bid - 38912;
        const float* S; short* D; int ldS, ldD, r0, c0;
        if (tb < 192) {                      // W1 head h: S[k][o] -> D[o][k]
            int hh = tb / 24, tt = tb % 24;
            int kt = tt >> 1, ot = tt & 1;
            S = W1 + (size_t)hh * 768 * 128; ldS = 128;
            D = W1T + (size_t)hh * 128 * 768; ldD = 768;
            r0 = kt * 64; c0 = ot * 64;
        } else {                             // W2: S[k][n] -> D[n][k]
            int tt = tb - 192;
            int kt = tt >> 1, nt = tt & 1;
            S = W2; ldS = 128;
            D = W2T; ldD = 1024;
            r0 = kt * 64; c0 = nt * 64;
        }
        int tr = t >> 6, tc = t & 63;
#pragma unroll
        for (int s = 0; s < 16; s++) {
            int r = s * 4 + tr;
            tileT[tc][r] = f2bf(S[(size_t)(r0 + r) * ldS + c0 + tc]);
        }
        __syncthreads();
#pragma unroll
        for (int s = 0; s < 16; s++) {
            int dr = s * 4 + tr;
            D[(size_t)(c0 + dr) * ldD + r0 + tc] = tileT[dr][tc];
        }
    }
}

// ---------------- bf16 MFMA GEMM 128x128, BK=64 pair, XCD-swz ------------------
// Layer-1 specialized: fused s1/s2 epilogue; coalesced C-store via LDS bounce.
__global__ __launch_bounds__(256) void k_gemm_bt(
        const short* __restrict__ A, const short* __restrict__ Bt,
        short* __restrict__ Ct, int K, int Ncols,
        const float* __restrict__ a1, const float* __restrict__ a2,
        float* __restrict__ s1, float* __restrict__ s2) {
    int tid = threadIdx.x, wave = tid >> 6, lane = tid & 63;
    int lr = lane & 15, lg = lane >> 4;
    int flat = blockIdx.y * gridDim.x + blockIdx.x;
    int chunkw = (gridDim.x * gridDim.y) >> 3;
    int swz = (flat & 7) * chunkw + (flat >> 3);
    int bx = swz % gridDim.x, by = swz / gridDim.x;
    int m0 = bx * 128, n0 = by * 128;
    int wm = (wave >> 1) * 64, wn = (wave & 1) * 64;
    __shared__ short lsA[2][128 * 64], lsB[2][128 * 64];
    __shared__ float sred1[2][128], sred2[2][128];
    f32x4 acc[4][4];
#pragma unroll
    for (int i = 0; i < 4; i++)
#pragma unroll
        for (int j = 0; j < 4; j++) acc[i][j] = (f32x4){0.f, 0.f, 0.f, 0.f};

    auto stage = [&](int bufsel, int k0) {
#pragma unroll
        for (int s = 0; s < 4; s++) {
            int chunk = s * 256 + tid;          // 1024 chunks of 16B per matrix
            int r = chunk >> 3, c = chunk & 7;
            int csrc = c ^ (r & 7);             // inverse-swizzled source
            gload_lds16(A + (size_t)(m0 + r) * K + k0 + csrc * 8, &lsA[bufsel][chunk * 8]);
            gload_lds16(Bt + (size_t)(n0 + r) * K + k0 + csrc * 8, &lsB[bufsel][chunk * 8]);
        }
    };
    auto compute = [&](const short* la, const short* lb) {
#pragma unroll
        for (int kk = 0; kk < 2; kk++) {
            short8 a[4], bb[4];
#pragma unroll
            for (int f = 0; f < 4; f++) {
                int ra = wm + f * 16 + lr, rb = wn + f * 16 + lr;
                a[f]  = *(const short8*)(la + ra * 64 + (((kk * 4 + lg) ^ (ra & 7)) * 8));
                bb[f] = *(const short8*)(lb + rb * 64 + (((kk * 4 + lg) ^ (rb & 7)) * 8));
            }
#pragma unroll
            for (int fm = 0; fm < 4; fm++)
#pragma unroll
                for (int fn = 0; fn < 4; fn++)
                    acc[fm][fn] = __builtin_amdgcn_mfma_f32_16x16x32_bf16(a[fm], bb[fn], acc[fm][fn], 0, 0, 0);
        }
    };
    stage(0, 0);
    __syncthreads();
    for (int k2 = 0; k2 < K; k2 += 128) {       // requires K % 128 == 0
        stage(1, k2 + 64);
        compute(lsA[0], lsB[0]);
        __syncthreads();
        if (k2 + 128 < K) stage(0, k2 + 128);
        compute(lsA[1], lsB[1]);
        __syncthreads();
    }
    // C-store via LDS bounce: stg[n_local][i4 swizzled] -> 256B-contiguous writes
    short* stg = &lsA[0][0];                    // 32KB, free after K-loop
#pragma unroll
    for (int fm = 0; fm < 4; fm++) {
#pragma unroll
        for (int fn = 0; fn < 4; fn++) {
            int nl = wn + fn * 16 + lr;
            int i4w = (wm + fm * 16 + lg * 4) >> 2;
            short4v st;
            st[0] = f2bf(acc[fm][fn][0]); st[1] = f2bf(acc[fm][fn][1]);
            st[2] = f2bf(acc[fm][fn][2]); st[3] = f2bf(acc[fm][fn][3]);
            *(short4v*)(stg + (nl * 32 + (i4w ^ (nl & 31))) * 4) = st;
        }
    }
    __syncthreads();
    size_t gbase = ((size_t)(m0 >> 10) * Ncols + n0) * 1024 + (m0 & 1023);
#pragma unroll
    for (int it = 0; it < 8; it++) {
        int idx8 = it * 256 + tid;              // 2048 units of 16B
        int nl = idx8 >> 4, p = idx8 & 15;
        int i4a = 2 * p, i4b = 2 * p + 1;
        short4v lo = *(short4v*)(stg + (nl * 32 + (i4a ^ (nl & 31))) * 4);
        short4v hi = *(short4v*)(stg + (nl * 32 + (i4b ^ (nl & 31))) * 4);
        short8 v;
#pragma unroll
        for (int r = 0; r < 4; r++) { v[r] = lo[r]; v[r + 4] = hi[r]; }
        *(short8*)(Ct + gbase + (size_t)nl * 1024 + p * 8) = v;
    }
    // fused s1/s2 epilogue (layer 1 only: a1 != nullptr)
    if (a1 != nullptr) {
        int h = by;                              // n-block == head
        float av1[4], av2[4];
#pragma unroll
        for (int fn = 0; fn < 4; fn++) {
            int o = wn + fn * 16 + lr;
            av1[fn] = a1[h * 128 + o];
            av2[fn] = a2[h * 128 + o];
        }
        int wcol = wave & 1;
#pragma unroll
        for (int fm = 0; fm < 4; fm++)
#pragma unroll
            for (int r = 0; r < 4; r++) {
                float v1 = acc[fm][0][r] * av1[0] + acc[fm][1][r] * av1[1]
                         + acc[fm][2][r] * av1[2] + acc[fm][3][r] * av1[3];
                float v2 = acc[fm][0][r] * av2[0] + acc[fm][1][r] * av2[1]
                         + acc[fm][2][r] * av2[2] + acc[fm][3][r] * av2[3];
#pragma unroll
                for (int off = 1; off < 16; off <<= 1) {
                    v1 += __shfl_xor(v1, off);
                    v2 += __shfl_xor(v2, off);
                }
                if (lr == 0) {
                    int il = wm + fm * 16 + lg * 4 + r;
                    sred1[wcol][il] = v1;
                    sred2[wcol][il] = v2;
                }
            }
        __syncthreads();
        if (tid < 128) {
            int b = m0 >> 10;
            int irow = (b * 8 + h) * 1024 + (m0 & 1023) + tid;
            s1[irow] = (sred1[0][tid] + sred1[1][tid]) * LOG2E;
            s2[irow] = (sred2[0][tid] + sred2[1][tid]) * LOG2E;
        }
    }
}

// ---------------- bf16 MFMA GEMM 64x64, BK=64 pair (layer-2) -------------------
__global__ __launch_bounds__(256) void k_gemm64(
        const short* __restrict__ A, const short* __restrict__ Bt,
        short* __restrict__ Ct, int K, int Ncols) {
    int tid = threadIdx.x, wave = tid >> 6, lane = tid & 63;
    int lr = lane & 15, lg = lane >> 4;
    int flat = blockIdx.y * gridDim.x + blockIdx.x;
    int chunkw = (gridDim.x * gridDim.y) >> 3;
    int swz = (flat & 7) * chunkw + (flat >> 3);
    int bx = swz % gridDim.x, by = swz / gridDim.x;
    int m0 = bx * 64, n0 = by * 64;
    int wm = (wave >> 1) * 32, wn = (wave & 1) * 32;
    __shared__ short lsA[2][64 * 64], lsB[2][64 * 64];
    f32x4 acc[2][2];
#pragma unroll
    for (int i = 0; i < 2; i++)
#pragma unroll
        for (int j = 0; j < 2; j++) acc[i][j] = (f32x4){0.f, 0.f, 0.f, 0.f};

    auto stage = [&](int bufsel, int k0) {
#pragma unroll
        for (int s = 0; s < 2; s++) {
            int chunk = s * 256 + tid;          // 512 chunks of 16B per matrix
            int r = chunk >> 3, c = chunk & 7;
            int csrc = c ^ (r & 7);
            gload_lds16(A + (size_t)(m0 + r) * K + k0 + csrc * 8, &lsA[bufsel][chunk * 8]);
            gload_lds16(Bt + (size_t)(n0 + r) * K + k0 + csrc * 8, &lsB[bufsel][chunk * 8]);
        }
    };
    auto compute = [&](const short* la, const short* lb) {
#pragma unroll
        for (int kk = 0; kk < 2; kk++) {
            short8 a[2], bb[2];
#pragma unroll
            for (int f = 0; f < 2; f++) {
                int ra = wm + f * 16 + lr, rb = wn + f * 16 + lr;
                a[f]  = *(const short8*)(la + ra * 64 + (((kk * 4 + lg) ^ (ra & 7)) * 8));
                bb[f] = *(const short8*)(lb + rb * 64 + (((kk * 4 + lg) ^ (rb & 7)) * 8));
            }
#pragma unroll
            for (int fm = 0; fm < 2; fm++)
#pragma unroll
                for (int fn = 0; fn < 2; fn++)
                    acc[fm][fn] = __builtin_amdgcn_mfma_f32_16x16x32_bf16(a[fm], bb[fn], acc[fm][fn], 0, 0, 0);
        }
    };
    stage(0, 0);
    __syncthreads();
    for (int k2 = 0; k2 < K; k2 += 128) {       // K % 128 == 0 (K=1024)
        stage(1, k2 + 64);
        compute(lsA[0], lsB[0]);
        __syncthreads();
        if (k2 + 128 < K) stage(0, k2 + 128);
        compute(lsA[1], lsB[1]);
        __syncthreads();
    }
#pragma unroll
    for (int fm = 0; fm < 2; fm++) {
        int mb = m0 + wm + fm * 16 + lg * 4;
        size_t obase = ((size_t)(mb >> 10) * Ncols) * 1024 + (mb & 1023);
#pragma unroll
        for (int fn = 0; fn < 2; fn++) {
            int n = n0 + wn + fn * 16 + lr;
            short4v st;
            st[0] = f2bf(acc[fm][fn][0]); st[1] = f2bf(acc[fm][fn][1]);
            st[2] = f2bf(acc[fm][fn][2]); st[3] = f2bf(acc[fm][fn][3]);
            *(short4v*)(Ct + obase + (size_t)n * 1024) = st;
        }
    }
}

// ---------------- GAT layer-1 attention: 8 waves x 16 i, s2 in LDS -------------
// LDS-staged h (dbuf, swizzled); psum via ones-MFMA; XCD-swizzled grid.
// Empirical optimum (R10/R13/R14/R19 neighbors all lose): VGPR 52, 16 waves/CU.
__global__ __launch_bounds__(512) void k_attn1(
        const short* __restrict__ ht, const unsigned* __restrict__ adjb,
        const float* __restrict__ s1, const float* __restrict__ s2,
        short* __restrict__ out) {
    int flat = blockIdx.y * 8 + blockIdx.x;
    int swz = (flat & 7) * 64 + (flat >> 3);    // 512 blocks: bijective
    int bh = swz >> 3, bxi = swz & 7;
    int b = bh >> 3, h = bh & 7;
    int tid = threadIdx.x, wave = tid >> 6, lane = tid & 63;
    int lr = lane & 15, lg = lane >> 4;
    int ic = bxi * 128 + wave * 16 + lr;
    int row = bh * 1024 + ic;
    float s1i = s1[row];                        // pre-scaled by log2e
    const unsigned long long* abrow =
        (const unsigned long long*)(adjb + ((size_t)(b << 10) + ic) * 32);
    const float* s2r = s2 + bh * 1024;
    const short* hbase = ht + (size_t)bh * 131072;

    __shared__ short lsh[2][16384];   // [128 o][128 j] bf16, chunk-XOR swizzled
    __shared__ float ls2[1024];       // staged s2 row (4KB)
    f32x4 acc[8];
#pragma unroll
    for (int f = 0; f < 8; f++) acc[f] = (f32x4){0.f, 0.f, 0.f, 0.f};
    f32x4 accs = (f32x4){0.f, 0.f, 0.f, 0.f};   // row-sum accumulator
    short8 ones8;
#pragma unroll
    for (int e = 0; e < 8; e++) ones8[e] = (short)0x3F80;   // bf16 1.0

    auto stage = [&](int bufsel, int j0) {
#pragma unroll
        for (int s = 0; s < 4; s++) {
            int chunk = s * 512 + tid;       // 2048 chunks of 16B
            int r = chunk >> 4, c = chunk & 15;
            int csrc = c ^ (r & 15);         // inverse-swizzle the SOURCE
            gload_lds16(hbase + (size_t)r * 1024 + j0 + csrc * 8,
                        &lsh[bufsel][chunk * 8]);
        }
    };
    auto compute = [&](const short* ls, int j0) {
        unsigned long long aw0 = abrow[j0 >> 6], aw1 = abrow[(j0 >> 6) + 1];
#pragma unroll
        for (int kk = 0; kk < 4; kk++) {
            int jb = j0 + kk * 32 + lg * 8;
            f32x4 t0 = *(const f32x4*)(&ls2[jb]);
            f32x4 t1 = *(const f32x4*)(&ls2[jb + 4]);
            unsigned long long aw = (kk < 2) ? aw0 : aw1;
            unsigned bits = (unsigned)(aw >> ((kk & 1) * 32 + lg * 8)) & 0xFFu;
            float pv[8];
#pragma unroll
            for (int e = 0; e < 8; e++) {
                float sv = e < 4 ? t0[e] : t1[e & 3];
                float ee = s1i + sv;
                ee = fmaxf(ee, ALPHA * ee);
                float p = fexp2(ee);
                pv[e] = ((bits >> e) & 1) ? p : 0.f;
            }
            int4v pw;
#pragma unroll
            for (int w = 0; w < 4; w++) {
                int d;
                asm("v_cvt_pk_bf16_f32 %0, %1, %2"
                    : "=v"(d) : "v"(pv[2 * w]), "v"(pv[2 * w + 1]));
                pw[w] = d;
            }
            short8 pb = __builtin_bit_cast(short8, pw);
            accs = __builtin_amdgcn_mfma_f32_16x16x32_bf16(ones8, pb, accs, 0, 0, 0);
#pragma unroll
            for (int fm = 0; fm < 8; fm++) {
                int r = fm * 16 + lr;
                int ck = (kk * 4 + lg) ^ (r & 15);   // swizzled read
                short8 af = *(const short8*)(ls + r * 128 + ck * 8);
                acc[fm] = __builtin_amdgcn_mfma_f32_16x16x32_bf16(af, pb, acc[fm], 0, 0, 0);
            }
        }
    };

    // stage s2 once (waves 0-3: 64 chunks of 16B each)
    if (wave < 4) {
        gload_lds16(s2r + (size_t)(wave * 64 + lane) * 4, &ls2[wave * 256]);
    }
    stage(0, 0);
    __syncthreads();
    for (int t2 = 0; t2 < 1024; t2 += 256) {
        stage(1, t2 + 128);
        compute(lsh[0], t2);
        __syncthreads();
        if (t2 + 256 < 1024) stage(0, t2 + 256);
        compute(lsh[1], t2 + 128);
        __syncthreads();
    }
    // row-sum for i = ic sits in every row of the ones-MFMA output (col = lr)
    float rdi = 1.f / accs[0];
    size_t orow = ((size_t)(b << 10) + ic) * 1024 + h * 128;
#pragma unroll
    for (int fm = 0; fm < 8; fm++) {
        int ob = (fm << 4) + lg * 4;
        short4v st;
#pragma unroll
        for (int r = 0; r < 4; r++) {
            float x = acc[fm][r] * rdi;
            x = x > 0.f ? x : expm1f(x);
            st[r] = f2bf(x);
        }
        *(short4v*)(out + orow + ob) = st;
    }
}

// ---------------- layer-2 attention, GATHERED rows, fused s1/s2 ----------------
__global__ __launch_bounds__(256) void k_attn2g(
        const short* __restrict__ h2t, const unsigned* __restrict__ adjb,
        const float* __restrict__ a1, const float* __restrict__ a2,
        const int* __restrict__ cidx, float* __restrict__ ghat) {
    int tile = blockIdx.x;      // 0..2
    int b = blockIdx.y;         // 0..7
    int tid = threadIdx.x, wave = tid >> 6, lane = tid & 63;
    int lr = lane & 15, lg = lane >> 4;

    __shared__ int nodes[16];
    __shared__ float ss1[16];
    __shared__ float sp1[16][17];
    __shared__ float ls2q[1024];
    __shared__ float sps[4][16];
    __shared__ float sacc[4][16][129];

    const short* hb = h2t + (size_t)b * 131072;

    if (tid < 16) {
        int pos = tile * 16 + tid;
        int nd0 = 0;
        if (pos >= 1 && pos <= 32) nd0 = cidx[b * 32 + pos - 1];
        nodes[tid] = nd0;
    }
    // s2 for this wave's j-quarter (fp32 accum, LOG2E-scaled)
    {
        int j4 = wave * 256 + lane * 4;
        const short* base = hb + j4;
        f32x4 a2v = {0.f, 0.f, 0.f, 0.f};
#pragma unroll 8
        for (int o = 0; o < 128; o++) {
            short4v v = *(const short4v*)(base + ((size_t)o << 10));
            float w2 = a2[o];
#pragma unroll
            for (int r = 0; r < 4; r++) a2v[r] += b2f(v[r]) * w2;
        }
#pragma unroll
        for (int r = 0; r < 4; r++) a2v[r] *= LOG2E;
        *(f32x4*)(&ls2q[j4]) = a2v;
    }
    __syncthreads();
    // s1 for the 16 gathered nodes: thread t -> node t&15, o-octet t>>4
    {
        int nd1 = nodes[tid & 15];
        int oc = tid >> 4;
        float p1 = 0.f;
#pragma unroll
        for (int oo = 0; oo < 8; oo++) {
            int o = oc * 8 + oo;
            p1 += b2f(hb[((size_t)o << 10) + nd1]) * a1[o];
        }
        sp1[oc][tid & 15] = p1;
    }
    __syncthreads();
    if (tid < 16) {
        float s = 0.f;
#pragma unroll
        for (int oc = 0; oc < 16; oc++) s += sp1[oc][tid];
        ss1[tid] = s * LOG2E;
    }
    __syncthreads();

    int nd = nodes[lr];
    float s1i = ss1[lr];
    const unsigned long long* abrow =
        (const unsigned long long*)(adjb + ((size_t)(b << 10) + nd) * 32);
    f32x4 acc[8];
#pragma unroll
    for (int f = 0; f < 8; f++) acc[f] = (f32x4){0.f, 0.f, 0.f, 0.f};
    float psum = 0.f;

    for (int j0 = wave * 256; j0 < wave * 256 + 256; j0 += 32) {
        int jb = j0 + lg * 8;
        f32x4 t0 = *(const f32x4*)(&ls2q[jb]);
        f32x4 t1 = *(const f32x4*)(&ls2q[jb + 4]);
        unsigned bits = (unsigned)(abrow[j0 >> 6] >> ((j0 & 32) + lg * 8)) & 0xFFu;
        short8 pb;
#pragma unroll
        for (int e = 0; e < 8; e++) {
            float sv = e < 4 ? t0[e] : t1[e & 3];
            float ee = s1i + sv;
            ee = fmaxf(ee, ALPHA * ee);
            float p = fexp2(ee);
            p = ((bits >> e) & 1) ? p : 0.f;
            psum += p;
            pb[e] = f2bf(p);
        }
#pragma unroll
        for (int fm = 0; fm < 8; fm++) {
            short8 af = *(const short8*)(hb + (size_t)(fm * 16 + lr) * 1024 + jb);
            acc[fm] = __builtin_amdgcn_mfma_f32_16x16x32_bf16(af, pb, acc[fm], 0, 0, 0);
        }
    }
    psum += __shfl_xor(psum, 16);
    psum += __shfl_xor(psum, 32);
    if (lg == 0) sps[wave][lr] = psum;
#pragma unroll
    for (int fm = 0; fm < 8; fm++)
#pragma unroll
        for (int r = 0; r < 4; r++)
            sacc[wave][lr][fm * 16 + lg * 4 + r] = acc[fm][r];
    __syncthreads();
    for (int e = tid; e < 2048; e += 256) {
        int li = e >> 7, o = e & 127;
        float sum = sps[0][li] + sps[1][li] + sps[2][li] + sps[3][li];
        float v = (sacc[0][li][o] + sacc[1][li][o] + sacc[2][li][o] + sacc[3][li][o]) / sum;
        v = v > 0.f ? v : expm1f(v);
        ghat[((size_t)b * 48 + tile * 16 + li) * 128 + o] = v;
    }
}

// ---------------- K/V projections, gload_lds-staged weight slices --------------
__global__ __launch_bounds__(256) void k_qkv(
        const float* __restrict__ ghat,
        const float* __restrict__ wk, const float* __restrict__ bk,
        const float* __restrict__ wvp, const float* __restrict__ bv,
        float* __restrict__ Kp, float* __restrict__ Vp) {
    int b = blockIdx.y, rg = blockIdx.x & 7, o0 = (blockIdx.x >> 3) * 64;
    int t = threadIdx.x, wvi = t >> 6, ln = t & 63;
    __shared__ float sx[4][128];
    __shared__ float sWk[128 * 64], sWv[128 * 64];

    if (wvi < 2) {
        int cb = wvi * 64;
        gload_lds16(ghat + ((size_t)b * 48 + 1 + rg * 4) * 128 + (size_t)(cb + ln) * 4,
                    (float*)sx + cb * 4);
    }
#pragma unroll
    for (int s = 0; s < 8; s++) {
        int cb = s * 256 + wvi * 64;
        int q = cb + ln, rw = q >> 4, c4 = q & 15;
        gload_lds16(wk  + (size_t)rw * 128 + o0 + c4 * 4, &sWk[cb * 4]);
        gload_lds16(wvp + (size_t)rw * 128 + o0 + c4 * 4, &sWv[cb * 4]);
    }
    __syncthreads();
    int o = o0 + ln;
    float ka = bk[o], va = bv[o];
#pragma unroll 32
    for (int c = 0; c < 128; c++) {
        float x = sx[wvi][c];
        ka += x * sWk[c * 64 + ln];
        va += x * sWv[c * 64 + ln];
    }
    int r = rg * 4 + wvi;
    Kp[((size_t)b * 32 + r) * 128 + o] = ka;
    Vp[((size_t)b * 32 + r) * 128 + o] = va;
}

// ---------------- tail: Qproj + MHA + wo + p1 + LN + relu -> tvec --------------
__global__ __launch_bounds__(256) void k_tail(
        const float* __restrict__ ghat, const float* __restrict__ Kp,
        const float* __restrict__ Vp,
        const float* __restrict__ wq, const float* __restrict__ bq,
        const float* __restrict__ wo, const float* __restrict__ bo,
        const float* __restrict__ p1w, const float* __restrict__ p1b,
        const float* __restrict__ lng, const float* __restrict__ lnb,
        float* __restrict__ tvec) {
    int b = blockIdx.x, t = threadIdx.x;
    int wvi = t >> 6, ln = t & 63;
    __shared__ float sq[128], sQ[128], sK[32][128], sV[32][128];
    __shared__ float sP[4][33], sO[128], sT[128], sZ[128];
    __shared__ float sred[2];
    __shared__ float sW[128 * 128];

#pragma unroll
    for (int s = 0; s < 4; s++) {
        int cb = s * 256 + wvi * 64;
        gload_lds16(Kp + (size_t)b * 4096 + (size_t)(cb + ln) * 4, (float*)sK + cb * 4);
        gload_lds16(Vp + (size_t)b * 4096 + (size_t)(cb + ln) * 4, (float*)sV + cb * 4);
    }
#pragma unroll
    for (int s = 0; s < 16; s++) {
        int cb = s * 256 + wvi * 64;
        gload_lds16(wq + (size_t)(cb + ln) * 4, &sW[cb * 4]);
    }
    if (t < 128) sq[t] = ghat[(size_t)b * 48 * 128 + t];
    __syncthreads();
    if (t < 128) {
        float a0 = 0.f, a1 = 0.f, a2 = 0.f, a3 = 0.f;
#pragma unroll
        for (int c = 0; c < 128; c += 4) {
            a0 += sq[c]     * sW[c * 128 + t];
            a1 += sq[c + 1] * sW[(c + 1) * 128 + t];
            a2 += sq[c + 2] * sW[(c + 2) * 128 + t];
            a3 += sq[c + 3] * sW[(c + 3) * 128 + t];
        }
        sQ[t] = bq[t] + ((a0 + a1) + (a2 + a3));
    }
    __syncthreads();
#pragma unroll
    for (int s = 0; s < 16; s++) {
        int cb = s * 256 + wvi * 64;
        gload_lds16(wo + (size_t)(cb + ln) * 4, &sW[cb * 4]);
    }
    if (t < 128) {
        int hh = t >> 5, jj = t & 31;
        float s = 0.f;
#pragma unroll
        for (int d = 0; d < 32; d++) s += sQ[hh * 32 + d] * sK[jj][hh * 32 + d];
        s *= 0.17677669529663687f;
        float m = s;
#pragma unroll
        for (int off = 16; off > 0; off >>= 1) m = fmaxf(m, __shfl_xor(m, off, 32));
        float p = __expf(s - m);
        float sum = p;
#pragma unroll
        for (int off = 16; off > 0; off >>= 1) sum += __shfl_xor(sum, off, 32);
        sP[hh][jj] = p / sum;
    }
    __syncthreads();
    if (t < 128) {
        int hh = t >> 5;
        float s = 0.f;
#pragma unroll
        for (int jj = 0; jj < 32; jj++) s += sP[hh][jj] * sV[jj][t];
        sO[t] = s;
    }
    __syncthreads();
    if (t < 128) {
        float a0 = 0.f, a1 = 0.f, a2 = 0.f, a3 = 0.f;
#pragma unroll
        for (int c = 0; c < 128; c += 4) {
            a0 += sO[c]     * sW[c * 128 + t];
            a1 += sO[c + 1] * sW[(c + 1) * 128 + t];
            a2 += sO[c + 2] * sW[(c + 2) * 128 + t];
            a3 += sO[c + 3] * sW[(c + 3) * 128 + t];
        }
        sT[t] = bo[t] + ((a0 + a1) + (a2 + a3));
    }
    __syncthreads();
#pragma unroll
    for (int s = 0; s < 16; s++) {
        int cb = s * 256 + wvi * 64;
        gload_lds16(p1w + (size_t)(cb + ln) * 4, &sW[cb * 4]);
    }
    __syncthreads();
    if (t < 128) {
        float a0 = 0.f, a1 = 0.f, a2 = 0.f, a3 = 0.f;
#pragma unroll
        for (int c = 0; c < 128; c += 4) {
            a0 += sT[c]     * sW[c * 128 + t];
            a1 += sT[c + 1] * sW[(c + 1) * 128 + t];
            a2 += sT[c + 2] * sW[(c + 2) * 128 + t];
            a3 += sT[c + 3] * sW[(c + 3) * 128 + t];
        }
        sZ[t] = p1b[t] + ((a0 + a1) + (a2 + a3));
    }
    __syncthreads();
    if (t < 64) {
        float v = sZ[t] + sZ[t + 64];
#pragma unroll
        for (int off = 32; off > 0; off >>= 1) v += __shfl_xor(v, off);
        if (t == 0) sred[0] = v * (1.f / 128.f);
    }
    __syncthreads();
    float mu = sred[0];
    if (t < 64) {
        float d1 = sZ[t] - mu, d2 = sZ[t + 64] - mu;
        float v = d1 * d1 + d2 * d2;
#pragma unroll
        for (int off = 32; off > 0; off >>= 1) v += __shfl_xor(v, off);
        if (t == 0) sred[1] = v * (1.f / 128.f);
    }
    __syncthreads();
    float rstd = rsqrtf(sred[1] + 1e-5f);
    if (t < 128) {
        float z = (sZ[t] - mu) * rstd * lng[t] + lnb[t];
        tvec[b * 128 + t] = fmaxf(z, 0.f);
    }
}

// ---------------- p2 projection: 48 blocks, gload_lds weight tiles -------------
__global__ __launch_bounds__(256) void k_p2(
        const float* __restrict__ tvec, const float* __restrict__ p2w,
        const float* __restrict__ p2b, float* __restrict__ out) {
    int jj0 = blockIdx.x * 128, b = blockIdx.y;
    int t = threadIdx.x, wvi = t >> 6, ln = t & 63;
    __shared__ float sT[128];
    __shared__ float sW[128 * 128];

#pragma unroll
    for (int s = 0; s < 16; s++) {
        int cb = s * 256 + wvi * 64;
        int q = cb + ln, c = q >> 5, c4 = q & 31;
        gload_lds16(p2w + (size_t)c * 768 + jj0 + c4 * 4, &sW[cb * 4]);
    }
    if (t < 128) sT[t] = tvec[b * 128 + t];
    __syncthreads();
    if (t < 128) {
        float a0 = 0.f, a1 = 0.f, a2 = 0.f, a3 = 0.f;
#pragma unroll
        for (int c = 0; c < 128; c += 4) {
            a0 += sT[c]     * sW[c * 128 + t];
            a1 += sT[c + 1] * sW[(c + 1) * 128 + t];
            a2 += sT[c + 2] * sW[(c + 2) * 128 + t];
            a3 += sT[c + 3] * sW[(c + 3) * 128 + t];
        }
        out[b * 768 + jj0 + t] = p2b[jj0 + t] + ((a0 + a1) + (a2 + a3));
    }
}

extern "C" void kernel_launch(void* const* d_in, const int* in_sizes, int n_in,
                              void* d_out, int out_size, void* d_ws, size_t ws_size,
                              hipStream_t stream) {
    const float* x   = (const float*)d_in[0];
    const int*  adj  = (const int*)d_in[1];
    const int*  cidx = (const int*)d_in[2];
    const float* W1  = (const float*)d_in[3];
    const float* a11 = (const float*)d_in[4];
    const float* a21 = (const float*)d_in[5];
    const float* W2  = (const float*)d_in[6];
    const float* a12 = (const float*)d_in[7];
    const float* a22 = (const float*)d_in[8];
    const float* wq = (const float*)d_in[9];  const float* bq = (const float*)d_in[10];
    const float* wk = (const float*)d_in[11]; const float* bk = (const float*)d_in[12];
    const float* wv = (const float*)d_in[13]; const float* bv = (const float*)d_in[14];
    const float* wo = (const float*)d_in[15]; const float* bo = (const float*)d_in[16];
    const float* p1w = (const float*)d_in[17]; const float* p1b = (const float*)d_in[18];
    const float* lng = (const float*)d_in[19]; const float* lnb = (const float*)d_in[20];
    const float* p2w = (const float*)d_in[21]; const float* p2b = (const float*)d_in[22];
    float* out = (float*)d_out;

    char* ws = (char*)d_ws;
    size_t off = 0;
    auto alloc = [&](size_t bytes) -> char* {
        char* p = ws + off;
        off = (off + bytes + 255) & ~(size_t)255;
        return p;
    };
    short* Xb   = (short*)alloc(8192ull * 768 * 2);
    short* W1T  = (short*)alloc(1024ull * 768 * 2);
    short* W2T  = (short*)alloc(128ull * 1024 * 2);
    unsigned* adjb = (unsigned*)alloc(8ull * 1024 * 32 * 4);
    short* h1t  = (short*)alloc(64ull * 128 * 1024 * 2);
    float* s1a  = (float*)alloc(64ull * 1024 * 4);
    float* s2a  = (float*)alloc(64ull * 1024 * 4);
    short* hcat = (short*)alloc(8192ull * 1024 * 2);
    short* h2t  = (short*)alloc(8ull * 128 * 1024 * 2);
    float* ghat = (float*)alloc(8ull * 48 * 128 * 4);
    float* Kp   = (float*)alloc(8ull * 32 * 128 * 4);
    float* Vp   = (float*)alloc(8ull * 32 * 128 * 4);
    float* tvec = (float*)alloc(8ull * 128 * 4);
    if (off > ws_size) return;

    // fused prep: adjbits | cast | tiled W transposes
    k_prep<<<39136, 256, 0, stream>>>(adj, adjb, x, Xb, W1, W1T, W2, W2T);

    // layer 1 (GEMM with fused s1/s2 epilogue)
    k_gemm_bt<<<dim3(64, 8), 256, 0, stream>>>(Xb, W1T, h1t, 768, 1024,
                                               a11, a21, s1a, s2a);
    k_attn1<<<dim3(8, 64), 512, 0, stream>>>(h1t, adjb, s1a, s2a, hcat);

    // layer 2 (GEMM full; attention fused with s1/s2 for gathered rows)
    k_gemm64<<<dim3(128, 2), 256, 0, stream>>>(hcat, W2T, h2t, 1024, 128);
    k_attn2g<<<dim3(3, 8), 256, 0, stream>>>(h2t, adjb, a12, a22, cidx, ghat);

    // tail
    k_qkv<<<dim3(16, 8), 256, 0, stream>>>(ghat, wk, bk, wv, bv, Kp, Vp);
    k_tail<<<8, 256, 0, stream>>>(ghat, Kp, Vp, wq, bq, wo, bo,
                                  p1w, p1b, lng, lnb, tvec);
    k_p2<<<dim3(6, 8), 256, 0, stream>>>(tvec, p2w, p2b, out);
}